// Round 1
// baseline (869.431 us; speedup 1.0000x reference)
//
#include <hip/hip_runtime.h>
#include <cstdint>
#include <cstddef>

// ---------------- degree count ----------------
__global__ void k_deg(const int* __restrict__ dst, int E, int* __restrict__ cnt) {
    int i = blockIdx.x * blockDim.x + threadIdx.x;
    int stride = gridDim.x * blockDim.x;
    for (; i < E; i += stride) atomicAdd(&cnt[dst[i]], 1);
}

// dinv[i] = rsqrt(indeg + 1)  (self-loop included; always >= 1)
__global__ void k_dinv(const int* __restrict__ cnt, float* __restrict__ dinv, int n) {
    int i = blockIdx.x * blockDim.x + threadIdx.x;
    if (i < n) dinv[i] = rsqrtf((float)(cnt[i] + 1));
}

// ---------------- exclusive scan (single block, 1024 threads) ----------------
__global__ void k_scan(const int* __restrict__ cnt, int n, int* __restrict__ offs) {
    __shared__ int sh[1024];
    __shared__ int carry;
    if (threadIdx.x == 0) carry = 0;
    __syncthreads();
    for (int base = 0; base < n; base += 1024) {
        int i = base + (int)threadIdx.x;
        int v = (i < n) ? cnt[i] : 0;
        sh[threadIdx.x] = v;
        __syncthreads();
        for (int o = 1; o < 1024; o <<= 1) {
            int t = (threadIdx.x >= (unsigned)o) ? sh[threadIdx.x - o] : 0;
            __syncthreads();
            sh[threadIdx.x] += t;
            __syncthreads();
        }
        if (i < n) offs[i] = carry + sh[threadIdx.x] - v;  // exclusive
        __syncthreads();
        if (threadIdx.x == 0) carry += sh[1023];
        __syncthreads();
    }
    if (threadIdx.x == 0) offs[n] = carry;
}

// ---------------- CSR fill ----------------
__global__ void k_fill(const int* __restrict__ src, const int* __restrict__ dst, int E,
                       const int* __restrict__ offs, int* __restrict__ cur,
                       int* __restrict__ csr_src) {
    int i = blockIdx.x * blockDim.x + threadIdx.x;
    int stride = gridDim.x * blockDim.x;
    for (; i < E; i += stride) {
        int d = dst[i];
        int p = atomicAdd(&cur[d], 1);
        csr_src[offs[d] + p] = src[i];
    }
}

// ---------------- GEMM: C[n,128] = f(A)[n,128] @ W[128,128] ----------------
// f = identity if ss==null, else per-col BN+ReLU: relu(a*ss[c] + ss[128+c])
__global__ __launch_bounds__(256) void k_gemm(
        const float* __restrict__ A, const float* __restrict__ W,
        const float* __restrict__ ss, float* __restrict__ C, int n) {
    __shared__ float sW[128 * 128];   // 64 KB
    __shared__ float sA[64 * 132];    // 33 KB, padded stride 132 (16B aligned, 2-way banks)
    const int tid = threadIdx.x;

    for (int i = tid; i < 128 * 128 / 4; i += 256)
        ((float4*)sW)[i] = ((const float4*)W)[i];

    const int rowBase = blockIdx.x * 64;
    for (int i = tid; i < 2048; i += 256) {            // 64 rows * 32 float4
        int r = i >> 5, k4 = i & 31;
        int gr = rowBase + r;
        float4 v;
        if (gr < n) v = ((const float4*)A)[(size_t)gr * 32 + k4];
        else        v = make_float4(0.f, 0.f, 0.f, 0.f);
        if (ss) {
            int k = k4 * 4;
            v.x = fmaxf(fmaf(v.x, ss[k + 0], ss[128 + k + 0]), 0.f);
            v.y = fmaxf(fmaf(v.y, ss[k + 1], ss[128 + k + 1]), 0.f);
            v.z = fmaxf(fmaf(v.z, ss[k + 2], ss[128 + k + 2]), 0.f);
            v.w = fmaxf(fmaf(v.w, ss[k + 3], ss[128 + k + 3]), 0.f);
        }
        *(float4*)&sA[r * 132 + k4 * 4] = v;
    }
    __syncthreads();

    const int cgrp = tid & 15, rgrp = tid >> 4;
    const int c0 = cgrp * 4, r0 = rgrp * 4;   // cols c0..c0+3 and 64+c0..64+c0+3
    float acc[4][8];
    #pragma unroll
    for (int i = 0; i < 4; i++)
        #pragma unroll
        for (int j = 0; j < 8; j++) acc[i][j] = 0.f;

    for (int k = 0; k < 128; k += 4) {
        float av[4][4];
        #pragma unroll
        for (int i = 0; i < 4; i++) {
            float4 t = *(const float4*)&sA[(r0 + i) * 132 + k];
            av[i][0] = t.x; av[i][1] = t.y; av[i][2] = t.z; av[i][3] = t.w;
        }
        #pragma unroll
        for (int j = 0; j < 4; j++) {
            float4 w0 = *(const float4*)&sW[(k + j) * 128 + c0];
            float4 w1 = *(const float4*)&sW[(k + j) * 128 + 64 + c0];
            #pragma unroll
            for (int i = 0; i < 4; i++) {
                float a = av[i][j];
                acc[i][0] = fmaf(a, w0.x, acc[i][0]);
                acc[i][1] = fmaf(a, w0.y, acc[i][1]);
                acc[i][2] = fmaf(a, w0.z, acc[i][2]);
                acc[i][3] = fmaf(a, w0.w, acc[i][3]);
                acc[i][4] = fmaf(a, w1.x, acc[i][4]);
                acc[i][5] = fmaf(a, w1.y, acc[i][5]);
                acc[i][6] = fmaf(a, w1.z, acc[i][6]);
                acc[i][7] = fmaf(a, w1.w, acc[i][7]);
            }
        }
    }

    #pragma unroll
    for (int i = 0; i < 4; i++) {
        int gr = rowBase + r0 + i;
        if (gr < n) {
            *(float4*)&C[(size_t)gr * 128 + c0]      = make_float4(acc[i][0], acc[i][1], acc[i][2], acc[i][3]);
            *(float4*)&C[(size_t)gr * 128 + 64 + c0] = make_float4(acc[i][4], acc[i][5], acc[i][6], acc[i][7]);
        }
    }
}

// ---------------- gather-aggregate (one wave per node) ----------------
// out[d] = dinv[d] * ( dinv[d]*h[d] + sum_{e in CSR(d)} dinv[src]*h[src] ) + bias
__global__ __launch_bounds__(256) void k_gather(
        const float* __restrict__ h, const int* __restrict__ offs,
        const int* __restrict__ csr_src, const float* __restrict__ dinv,
        const float* __restrict__ bias, float* __restrict__ out, int n) {
    int node = (blockIdx.x * blockDim.x + threadIdx.x) >> 6;
    int lane = threadIdx.x & 63;
    if (node >= n) return;
    const float di = dinv[node];
    const int beg = offs[node], end = offs[node + 1];
    const int c = lane * 2;

    float2 hv = *(const float2*)&h[(size_t)node * 128 + c];
    float ax = di * hv.x, ay = di * hv.y;   // self loop (x dinv[d] again at the end)

    int e = beg;
    for (; e + 4 <= end; e += 4) {
        int s0 = csr_src[e + 0], s1 = csr_src[e + 1], s2 = csr_src[e + 2], s3 = csr_src[e + 3];
        float w0 = dinv[s0], w1 = dinv[s1], w2 = dinv[s2], w3 = dinv[s3];
        float2 v0 = *(const float2*)&h[(size_t)s0 * 128 + c];
        float2 v1 = *(const float2*)&h[(size_t)s1 * 128 + c];
        float2 v2 = *(const float2*)&h[(size_t)s2 * 128 + c];
        float2 v3 = *(const float2*)&h[(size_t)s3 * 128 + c];
        ax = fmaf(w0, v0.x, ax); ay = fmaf(w0, v0.y, ay);
        ax = fmaf(w1, v1.x, ax); ay = fmaf(w1, v1.y, ay);
        ax = fmaf(w2, v2.x, ax); ay = fmaf(w2, v2.y, ay);
        ax = fmaf(w3, v3.x, ax); ay = fmaf(w3, v3.y, ay);
    }
    for (; e < end; ++e) {
        int s = csr_src[e];
        float w = dinv[s];
        float2 v = *(const float2*)&h[(size_t)s * 128 + c];
        ax = fmaf(w, v.x, ax); ay = fmaf(w, v.y, ay);
    }
    float2 o;
    o.x = fmaf(di, ax, bias[c]);
    o.y = fmaf(di, ay, bias[c + 1]);
    *(float2*)&out[(size_t)node * 128 + c] = o;
}

// ---------------- BN stats: per-feature sum and sumsq ----------------
__global__ void k_stats(const float* __restrict__ h, int n, float* __restrict__ sums) {
    int c = threadIdx.x & 127;
    int half = threadIdx.x >> 7;
    float s = 0.f, s2 = 0.f;
    for (int r = blockIdx.x * 2 + half; r < n; r += gridDim.x * 2) {
        float v = h[(size_t)r * 128 + c];
        s += v; s2 = fmaf(v, v, s2);
    }
    __shared__ float sh[256], sh2[256];
    sh[threadIdx.x] = s; sh2[threadIdx.x] = s2;
    __syncthreads();
    if (half == 0) {
        atomicAdd(&sums[c],       s  + sh[threadIdx.x + 128]);
        atomicAdd(&sums[128 + c], s2 + sh2[threadIdx.x + 128]);
    }
}

// fold mean/var/gamma/beta into scale+shift
__global__ void k_bnparam(const float* __restrict__ sums, const float* __restrict__ g,
                          const float* __restrict__ be, int n, float* __restrict__ ss) {
    int c = threadIdx.x;
    float invn = 1.f / (float)n;
    float mean = sums[c] * invn;
    float var = sums[128 + c] * invn - mean * mean;
    float inv = rsqrtf(var + 1e-5f);
    float sc = g[c] * inv;
    ss[c] = sc;
    ss[128 + c] = be[c] - mean * sc;
}

// ---------------- head: sigmoid(relu(relu(bn2(h)) @ Wl + bl)) ----------------
__global__ __launch_bounds__(256) void k_final(
        const float* __restrict__ h, const float* __restrict__ ss,
        const float* __restrict__ Wl, const float* __restrict__ bl,
        float* __restrict__ out, int n) {
    int node = (blockIdx.x * blockDim.x + threadIdx.x) >> 6;
    int lane = threadIdx.x & 63;
    if (node >= n) return;
    int c = lane * 2;
    float2 v = *(const float2*)&h[(size_t)node * 128 + c];
    float a0 = fmaxf(fmaf(v.x, ss[c],     ss[128 + c]),     0.f);
    float a1 = fmaxf(fmaf(v.y, ss[c + 1], ss[128 + c + 1]), 0.f);
    float p = a0 * Wl[c] + a1 * Wl[c + 1];
    #pragma unroll
    for (int o = 32; o; o >>= 1) p += __shfl_xor(p, o);
    if (lane == 0) {
        float z = fmaxf(p + bl[0], 0.f);
        out[node] = 1.f / (1.f + expf(-z));
    }
}

extern "C" void kernel_launch(void* const* d_in, const int* in_sizes, int n_in,
                              void* d_out, int out_size, void* d_ws, size_t ws_size,
                              hipStream_t stream) {
    const float* x   = (const float*)d_in[0];
    const int*   ei  = (const int*)d_in[1];
    const float* W1  = (const float*)d_in[2];
    const float* b1  = (const float*)d_in[3];
    const float* g1  = (const float*)d_in[4];
    const float* be1 = (const float*)d_in[5];
    const float* W2  = (const float*)d_in[6];
    const float* b2  = (const float*)d_in[7];
    const float* g2  = (const float*)d_in[8];
    const float* be2 = (const float*)d_in[9];
    const float* Wl  = (const float*)d_in[10];
    const float* bl  = (const float*)d_in[11];

    const int N = in_sizes[0] / 128;
    const int E = in_sizes[1] / 2;
    const int* src  = ei;       // edge_index[0]
    const int* dstp = ei + E;   // edge_index[1]

    char* ws = (char*)d_ws;
    size_t off = 0;
    auto alloc = [&](size_t bytes) {
        void* p = ws + off;
        off += (bytes + 255) & ~(size_t)255;
        return p;
    };
    int*   cnt  = (int*)  alloc((size_t)N * 4);
    float* dinv = (float*)alloc((size_t)N * 4);
    int*   offs = (int*)  alloc((size_t)(N + 1) * 4);
    int*   cur  = (int*)  alloc((size_t)N * 4);
    int*   csr  = (int*)  alloc((size_t)E * 4);
    float* sums = (float*)alloc(512 * 4);   // [sum1,sq1,sum2,sq2]
    float* ss   = (float*)alloc(512 * 4);   // [scale1,shift1,scale2,shift2]
    float* hbuf = (float*)alloc((size_t)N * 128 * 4);
    float* abuf = (float*)alloc((size_t)N * 128 * 4);

    hipMemsetAsync(cnt,  0, (size_t)N * 4, stream);
    hipMemsetAsync(cur,  0, (size_t)N * 4, stream);
    hipMemsetAsync(sums, 0, 512 * 4, stream);

    // graph structure (shared by both conv layers)
    k_deg <<<2048, 256, 0, stream>>>(dstp, E, cnt);
    k_dinv<<<(N + 255) / 256, 256, 0, stream>>>(cnt, dinv, N);
    k_scan<<<1, 1024, 0, stream>>>(cnt, N, offs);
    k_fill<<<2048, 256, 0, stream>>>(src, dstp, E, offs, cur, csr);

    // layer 1
    k_gemm  <<<(N + 63) / 64, 256, 0, stream>>>(x, W1, nullptr, hbuf, N);
    k_gather<<<(N + 3) / 4, 256, 0, stream>>>(hbuf, offs, csr, dinv, b1, abuf, N);
    k_stats <<<512, 256, 0, stream>>>(abuf, N, sums);
    k_bnparam<<<1, 128, 0, stream>>>(sums, g1, be1, N, ss);

    // layer 2 (BN1+ReLU fused into GEMM2's A-load)
    k_gemm  <<<(N + 63) / 64, 256, 0, stream>>>(abuf, W2, ss, hbuf, N);
    k_gather<<<(N + 3) / 4, 256, 0, stream>>>(hbuf, offs, csr, dinv, b2, abuf, N);
    k_stats <<<512, 256, 0, stream>>>(abuf, N, sums + 256);
    k_bnparam<<<1, 128, 0, stream>>>(sums + 256, g2, be2, N, ss + 256);

    // head (BN2+ReLU fused)
    k_final<<<(N + 3) / 4, 256, 0, stream>>>(abuf, ss + 256, Wl, bl, (float*)d_out, N);
}

// Round 2
// 721.492 us; speedup vs baseline: 1.2050x; 1.2050x over previous
//
#include <hip/hip_runtime.h>
#include <cstdint>
#include <cstddef>

// ---------------- degree count ----------------
__global__ void k_deg(const int* __restrict__ dst, int E, int* __restrict__ cnt) {
    int i = blockIdx.x * blockDim.x + threadIdx.x;
    int stride = gridDim.x * blockDim.x;
    for (; i < E; i += stride) atomicAdd(&cnt[dst[i]], 1);
}

// dinv[i] = rsqrt(indeg + 1)  (self-loop included; always >= 1)
__global__ void k_dinv(const int* __restrict__ cnt, float* __restrict__ dinv, int n) {
    int i = blockIdx.x * blockDim.x + threadIdx.x;
    if (i < n) dinv[i] = rsqrtf((float)(cnt[i] + 1));
}

// ---------------- hierarchical exclusive scan ----------------
// pass 1: each block scans a 1024-element chunk (4 elems/thread), writes
//         local-exclusive values to offs and the chunk total to bsum.
__global__ __launch_bounds__(256) void k_scan_local(
        const int* __restrict__ cnt, int n,
        int* __restrict__ offs, int* __restrict__ bsum) {
    __shared__ int sh[256];
    const int base = blockIdx.x * 1024 + threadIdx.x * 4;
    int v[4];
    #pragma unroll
    for (int j = 0; j < 4; j++) { int g = base + j; v[j] = (g < n) ? cnt[g] : 0; }
    const int tsum = v[0] + v[1] + v[2] + v[3];
    sh[threadIdx.x] = tsum;
    __syncthreads();
    #pragma unroll
    for (int o = 1; o < 256; o <<= 1) {
        int t = (threadIdx.x >= (unsigned)o) ? sh[threadIdx.x - o] : 0;
        __syncthreads();
        sh[threadIdx.x] += t;
        __syncthreads();
    }
    int run = sh[threadIdx.x] - tsum;   // exclusive prefix of this thread's 4
    #pragma unroll
    for (int j = 0; j < 4; j++) {
        int g = base + j;
        if (g < n) offs[g] = run;
        run += v[j];
    }
    if (threadIdx.x == 255) bsum[blockIdx.x] = sh[255];
}

// pass 2: single block exclusive-scans the block sums (nb <= 1024), writes total.
__global__ __launch_bounds__(1024) void k_scan_bsum(
        int* __restrict__ bsum, int nb, int* __restrict__ total) {
    __shared__ int sh[1024];
    const int t = threadIdx.x;
    int v = (t < nb) ? bsum[t] : 0;
    sh[t] = v;
    __syncthreads();
    #pragma unroll
    for (int o = 1; o < 1024; o <<= 1) {
        int x = (t >= (unsigned)o) ? sh[t - o] : 0;
        __syncthreads();
        sh[t] += x;
        __syncthreads();
    }
    if (t < nb) bsum[t] = sh[t] - v;          // exclusive
    if (t == 1023) *total = sh[1023];          // grand total (= E)
}

// pass 3: add block offsets back.
__global__ __launch_bounds__(256) void k_scan_add(
        int* __restrict__ offs, int n, const int* __restrict__ bsum) {
    const int add = bsum[blockIdx.x];
    const int base = blockIdx.x * 1024;
    #pragma unroll
    for (int j = 0; j < 4; j++) {
        int g = base + threadIdx.x + j * 256;
        if (g < n) offs[g] += add;
    }
}

// ---------------- CSR fill ----------------
__global__ void k_fill(const int* __restrict__ src, const int* __restrict__ dst, int E,
                       const int* __restrict__ offs, int* __restrict__ cur,
                       int* __restrict__ csr_src) {
    int i = blockIdx.x * blockDim.x + threadIdx.x;
    int stride = gridDim.x * blockDim.x;
    for (; i < E; i += stride) {
        int d = dst[i];
        int p = atomicAdd(&cur[d], 1);
        csr_src[offs[d] + p] = src[i];
    }
}

// ---------------- GEMM: C[n,128] = f(A)[n,128] @ W[128,128] ----------------
// f = identity if ss==null, else per-col BN+ReLU: relu(a*ss[c] + ss[128+c])
__global__ __launch_bounds__(256) void k_gemm(
        const float* __restrict__ A, const float* __restrict__ W,
        const float* __restrict__ ss, float* __restrict__ C, int n) {
    __shared__ float sW[128 * 128];   // 64 KB
    __shared__ float sA[64 * 132];    // 33 KB, padded stride 132
    const int tid = threadIdx.x;

    for (int i = tid; i < 128 * 128 / 4; i += 256)
        ((float4*)sW)[i] = ((const float4*)W)[i];

    const int rowBase = blockIdx.x * 64;
    for (int i = tid; i < 2048; i += 256) {            // 64 rows * 32 float4
        int r = i >> 5, k4 = i & 31;
        int gr = rowBase + r;
        float4 v;
        if (gr < n) v = ((const float4*)A)[(size_t)gr * 32 + k4];
        else        v = make_float4(0.f, 0.f, 0.f, 0.f);
        if (ss) {
            int k = k4 * 4;
            v.x = fmaxf(fmaf(v.x, ss[k + 0], ss[128 + k + 0]), 0.f);
            v.y = fmaxf(fmaf(v.y, ss[k + 1], ss[128 + k + 1]), 0.f);
            v.z = fmaxf(fmaf(v.z, ss[k + 2], ss[128 + k + 2]), 0.f);
            v.w = fmaxf(fmaf(v.w, ss[k + 3], ss[128 + k + 3]), 0.f);
        }
        *(float4*)&sA[r * 132 + k4 * 4] = v;
    }
    __syncthreads();

    const int cgrp = tid & 15, rgrp = tid >> 4;
    const int c0 = cgrp * 4, r0 = rgrp * 4;
    float acc[4][8];
    #pragma unroll
    for (int i = 0; i < 4; i++)
        #pragma unroll
        for (int j = 0; j < 8; j++) acc[i][j] = 0.f;

    for (int k = 0; k < 128; k += 4) {
        float av[4][4];
        #pragma unroll
        for (int i = 0; i < 4; i++) {
            float4 t = *(const float4*)&sA[(r0 + i) * 132 + k];
            av[i][0] = t.x; av[i][1] = t.y; av[i][2] = t.z; av[i][3] = t.w;
        }
        #pragma unroll
        for (int j = 0; j < 4; j++) {
            float4 w0 = *(const float4*)&sW[(k + j) * 128 + c0];
            float4 w1 = *(const float4*)&sW[(k + j) * 128 + 64 + c0];
            #pragma unroll
            for (int i = 0; i < 4; i++) {
                float a = av[i][j];
                acc[i][0] = fmaf(a, w0.x, acc[i][0]);
                acc[i][1] = fmaf(a, w0.y, acc[i][1]);
                acc[i][2] = fmaf(a, w0.z, acc[i][2]);
                acc[i][3] = fmaf(a, w0.w, acc[i][3]);
                acc[i][4] = fmaf(a, w1.x, acc[i][4]);
                acc[i][5] = fmaf(a, w1.y, acc[i][5]);
                acc[i][6] = fmaf(a, w1.z, acc[i][6]);
                acc[i][7] = fmaf(a, w1.w, acc[i][7]);
            }
        }
    }

    #pragma unroll
    for (int i = 0; i < 4; i++) {
        int gr = rowBase + r0 + i;
        if (gr < n) {
            *(float4*)&C[(size_t)gr * 128 + c0]      = make_float4(acc[i][0], acc[i][1], acc[i][2], acc[i][3]);
            *(float4*)&C[(size_t)gr * 128 + 64 + c0] = make_float4(acc[i][4], acc[i][5], acc[i][6], acc[i][7]);
        }
    }
}

// ---------------- gather-aggregate (one wave per node) ----------------
__global__ __launch_bounds__(256) void k_gather(
        const float* __restrict__ h, const int* __restrict__ offs,
        const int* __restrict__ csr_src, const float* __restrict__ dinv,
        const float* __restrict__ bias, float* __restrict__ out, int n) {
    int node = (blockIdx.x * blockDim.x + threadIdx.x) >> 6;
    int lane = threadIdx.x & 63;
    if (node >= n) return;
    const float di = dinv[node];
    const int beg = offs[node], end = offs[node + 1];
    const int c = lane * 2;

    float2 hv = *(const float2*)&h[(size_t)node * 128 + c];
    float ax = di * hv.x, ay = di * hv.y;   // self loop

    int e = beg;
    for (; e + 4 <= end; e += 4) {
        int s0 = csr_src[e + 0], s1 = csr_src[e + 1], s2 = csr_src[e + 2], s3 = csr_src[e + 3];
        float w0 = dinv[s0], w1 = dinv[s1], w2 = dinv[s2], w3 = dinv[s3];
        float2 v0 = *(const float2*)&h[(size_t)s0 * 128 + c];
        float2 v1 = *(const float2*)&h[(size_t)s1 * 128 + c];
        float2 v2 = *(const float2*)&h[(size_t)s2 * 128 + c];
        float2 v3 = *(const float2*)&h[(size_t)s3 * 128 + c];
        ax = fmaf(w0, v0.x, ax); ay = fmaf(w0, v0.y, ay);
        ax = fmaf(w1, v1.x, ax); ay = fmaf(w1, v1.y, ay);
        ax = fmaf(w2, v2.x, ax); ay = fmaf(w2, v2.y, ay);
        ax = fmaf(w3, v3.x, ax); ay = fmaf(w3, v3.y, ay);
    }
    for (; e < end; ++e) {
        int s = csr_src[e];
        float w = dinv[s];
        float2 v = *(const float2*)&h[(size_t)s * 128 + c];
        ax = fmaf(w, v.x, ax); ay = fmaf(w, v.y, ay);
    }
    float2 o;
    o.x = fmaf(di, ax, bias[c]);
    o.y = fmaf(di, ay, bias[c + 1]);
    *(float2*)&out[(size_t)node * 128 + c] = o;
}

// ---------------- BN stats: per-feature sum and sumsq ----------------
__global__ void k_stats(const float* __restrict__ h, int n, float* __restrict__ sums) {
    int c = threadIdx.x & 127;
    int half = threadIdx.x >> 7;
    float s = 0.f, s2 = 0.f;
    for (int r = blockIdx.x * 2 + half; r < n; r += gridDim.x * 2) {
        float v = h[(size_t)r * 128 + c];
        s += v; s2 = fmaf(v, v, s2);
    }
    __shared__ float sh[256], sh2[256];
    sh[threadIdx.x] = s; sh2[threadIdx.x] = s2;
    __syncthreads();
    if (half == 0) {
        atomicAdd(&sums[c],       s  + sh[threadIdx.x + 128]);
        atomicAdd(&sums[128 + c], s2 + sh2[threadIdx.x + 128]);
    }
}

// fold mean/var/gamma/beta into scale+shift
__global__ void k_bnparam(const float* __restrict__ sums, const float* __restrict__ g,
                          const float* __restrict__ be, int n, float* __restrict__ ss) {
    int c = threadIdx.x;
    float invn = 1.f / (float)n;
    float mean = sums[c] * invn;
    float var = sums[128 + c] * invn - mean * mean;
    float inv = rsqrtf(var + 1e-5f);
    float sc = g[c] * inv;
    ss[c] = sc;
    ss[128 + c] = be[c] - mean * sc;
}

// ---------------- head: sigmoid(relu(relu(bn2(h)) @ Wl + bl)) ----------------
__global__ __launch_bounds__(256) void k_final(
        const float* __restrict__ h, const float* __restrict__ ss,
        const float* __restrict__ Wl, const float* __restrict__ bl,
        float* __restrict__ out, int n) {
    int node = (blockIdx.x * blockDim.x + threadIdx.x) >> 6;
    int lane = threadIdx.x & 63;
    if (node >= n) return;
    int c = lane * 2;
    float2 v = *(const float2*)&h[(size_t)node * 128 + c];
    float a0 = fmaxf(fmaf(v.x, ss[c],     ss[128 + c]),     0.f);
    float a1 = fmaxf(fmaf(v.y, ss[c + 1], ss[128 + c + 1]), 0.f);
    float p = a0 * Wl[c] + a1 * Wl[c + 1];
    #pragma unroll
    for (int o = 32; o; o >>= 1) p += __shfl_xor(p, o);
    if (lane == 0) {
        float z = fmaxf(p + bl[0], 0.f);
        out[node] = 1.f / (1.f + expf(-z));
    }
}

extern "C" void kernel_launch(void* const* d_in, const int* in_sizes, int n_in,
                              void* d_out, int out_size, void* d_ws, size_t ws_size,
                              hipStream_t stream) {
    const float* x   = (const float*)d_in[0];
    const int*   ei  = (const int*)d_in[1];
    const float* W1  = (const float*)d_in[2];
    const float* b1  = (const float*)d_in[3];
    const float* g1  = (const float*)d_in[4];
    const float* be1 = (const float*)d_in[5];
    const float* W2  = (const float*)d_in[6];
    const float* b2  = (const float*)d_in[7];
    const float* g2  = (const float*)d_in[8];
    const float* be2 = (const float*)d_in[9];
    const float* Wl  = (const float*)d_in[10];
    const float* bl  = (const float*)d_in[11];

    const int N = in_sizes[0] / 128;
    const int E = in_sizes[1] / 2;
    const int* src  = ei;       // edge_index[0]
    const int* dstp = ei + E;   // edge_index[1]

    const int NB = (N + 1023) / 1024;   // scan blocks (98 for N=100k)

    char* ws = (char*)d_ws;
    size_t off = 0;
    auto alloc = [&](size_t bytes) {
        void* p = ws + off;
        off += (bytes + 255) & ~(size_t)255;
        return p;
    };
    int*   cnt  = (int*)  alloc((size_t)N * 4);
    float* dinv = (float*)alloc((size_t)N * 4);
    int*   offs = (int*)  alloc((size_t)(N + 1) * 4);
    int*   cur  = (int*)  alloc((size_t)N * 4);
    int*   bsum = (int*)  alloc((size_t)NB * 4);
    int*   csr  = (int*)  alloc((size_t)E * 4);
    float* sums = (float*)alloc(512 * 4);   // [sum1,sq1,sum2,sq2]
    float* ss   = (float*)alloc(512 * 4);   // [scale1,shift1,scale2,shift2]
    float* hbuf = (float*)alloc((size_t)N * 128 * 4);
    float* abuf = (float*)alloc((size_t)N * 128 * 4);

    hipMemsetAsync(cnt,  0, (size_t)N * 4, stream);
    hipMemsetAsync(cur,  0, (size_t)N * 4, stream);
    hipMemsetAsync(sums, 0, 512 * 4, stream);

    // graph structure (shared by both conv layers)
    k_deg       <<<2048, 256, 0, stream>>>(dstp, E, cnt);
    k_dinv      <<<(N + 255) / 256, 256, 0, stream>>>(cnt, dinv, N);
    k_scan_local<<<NB, 256, 0, stream>>>(cnt, N, offs, bsum);
    k_scan_bsum <<<1, 1024, 0, stream>>>(bsum, NB, offs + N);
    k_scan_add  <<<NB, 256, 0, stream>>>(offs, N, bsum);
    k_fill      <<<2048, 256, 0, stream>>>(src, dstp, E, offs, cur, csr);

    // layer 1
    k_gemm  <<<(N + 63) / 64, 256, 0, stream>>>(x, W1, nullptr, hbuf, N);
    k_gather<<<(N + 3) / 4, 256, 0, stream>>>(hbuf, offs, csr, dinv, b1, abuf, N);
    k_stats <<<512, 256, 0, stream>>>(abuf, N, sums);
    k_bnparam<<<1, 128, 0, stream>>>(sums, g1, be1, N, ss);

    // layer 2 (BN1+ReLU fused into GEMM2's A-load)
    k_gemm  <<<(N + 63) / 64, 256, 0, stream>>>(abuf, W2, ss, hbuf, N);
    k_gather<<<(N + 3) / 4, 256, 0, stream>>>(hbuf, offs, csr, dinv, b2, abuf, N);
    k_stats <<<512, 256, 0, stream>>>(abuf, N, sums + 256);
    k_bnparam<<<1, 128, 0, stream>>>(sums + 256, g2, be2, N, ss + 256);

    // head (BN2+ReLU fused)
    k_final<<<(N + 3) / 4, 256, 0, stream>>>(abuf, ss + 256, Wl, bl, (float*)d_out, N);
}

// Round 3
// 625.755 us; speedup vs baseline: 1.3894x; 1.1530x over previous
//
#include <hip/hip_runtime.h>
#include <cstdint>
#include <cstddef>

typedef unsigned int uint;
typedef unsigned short ushort;

__device__ __forceinline__ ushort f2bf(float f) {          // RNE float->bf16
    uint b = __float_as_uint(f);
    return (ushort)((b + 0x7FFF + ((b >> 16) & 1)) >> 16);
}
__device__ __forceinline__ float bf_lo(uint u) { return __uint_as_float(u << 16); }
__device__ __forceinline__ float bf_hi(uint u) { return __uint_as_float(u & 0xFFFF0000u); }

// ---------------- degree count (ILP x4) ----------------
__global__ void k_deg(const int* __restrict__ dst, int E, int* __restrict__ cnt) {
    const int T = gridDim.x * blockDim.x;
    for (int i = blockIdx.x * blockDim.x + threadIdx.x; i < E; i += 4 * T) {
        int i1 = i + T, i2 = i + 2 * T, i3 = i + 3 * T;
        int d0 = dst[i];
        int d1 = (i1 < E) ? dst[i1] : -1;
        int d2 = (i2 < E) ? dst[i2] : -1;
        int d3 = (i3 < E) ? dst[i3] : -1;
        atomicAdd(&cnt[d0], 1);
        if (d1 >= 0) atomicAdd(&cnt[d1], 1);
        if (d2 >= 0) atomicAdd(&cnt[d2], 1);
        if (d3 >= 0) atomicAdd(&cnt[d3], 1);
    }
}

// dinv[i] = rsqrt(indeg + 1)
__global__ void k_dinv(const int* __restrict__ cnt, float* __restrict__ dinv, int n) {
    int i = blockIdx.x * blockDim.x + threadIdx.x;
    if (i < n) dinv[i] = rsqrtf((float)(cnt[i] + 1));
}

// ---------------- hierarchical exclusive scan ----------------
__global__ __launch_bounds__(256) void k_scan_local(
        const int* __restrict__ cnt, int n,
        int* __restrict__ offs, int* __restrict__ bsum) {
    __shared__ int sh[256];
    const int base = blockIdx.x * 1024 + threadIdx.x * 4;
    int v[4];
    #pragma unroll
    for (int j = 0; j < 4; j++) { int g = base + j; v[j] = (g < n) ? cnt[g] : 0; }
    const int tsum = v[0] + v[1] + v[2] + v[3];
    sh[threadIdx.x] = tsum;
    __syncthreads();
    #pragma unroll
    for (int o = 1; o < 256; o <<= 1) {
        int t = (threadIdx.x >= (unsigned)o) ? sh[threadIdx.x - o] : 0;
        __syncthreads();
        sh[threadIdx.x] += t;
        __syncthreads();
    }
    int run = sh[threadIdx.x] - tsum;
    #pragma unroll
    for (int j = 0; j < 4; j++) {
        int g = base + j;
        if (g < n) offs[g] = run;
        run += v[j];
    }
    if (threadIdx.x == 255) bsum[blockIdx.x] = sh[255];
}

__global__ __launch_bounds__(1024) void k_scan_bsum(
        int* __restrict__ bsum, int nb, int* __restrict__ total) {
    __shared__ int sh[1024];
    const int t = threadIdx.x;
    int v = (t < nb) ? bsum[t] : 0;
    sh[t] = v;
    __syncthreads();
    #pragma unroll
    for (int o = 1; o < 1024; o <<= 1) {
        int x = (t >= (unsigned)o) ? sh[t - o] : 0;
        __syncthreads();
        sh[t] += x;
        __syncthreads();
    }
    if (t < nb) bsum[t] = sh[t] - v;
    if (t == 1023) *total = sh[1023];
}

__global__ __launch_bounds__(256) void k_scan_add(
        int* __restrict__ offs, int n, const int* __restrict__ bsum) {
    const int add = bsum[blockIdx.x];
    const int base = blockIdx.x * 1024;
    #pragma unroll
    for (int j = 0; j < 4; j++) {
        int g = base + threadIdx.x + j * 256;
        if (g < n) offs[g] += add;
    }
}

// ---------------- CSR fill (ILP x4) ----------------
__global__ void k_fill(const int* __restrict__ src, const int* __restrict__ dst, int E,
                       const int* __restrict__ offs, int* __restrict__ cur,
                       int* __restrict__ csr_src) {
    const int T = gridDim.x * blockDim.x;
    for (int i = blockIdx.x * blockDim.x + threadIdx.x; i < E; i += 4 * T) {
        int i1 = i + T, i2 = i + 2 * T, i3 = i + 3 * T;
        int d0 = dst[i], s0 = src[i];
        int d1 = -1, s1 = 0, d2 = -1, s2 = 0, d3 = -1, s3 = 0;
        if (i1 < E) { d1 = dst[i1]; s1 = src[i1]; }
        if (i2 < E) { d2 = dst[i2]; s2 = src[i2]; }
        if (i3 < E) { d3 = dst[i3]; s3 = src[i3]; }
        int p0 = atomicAdd(&cur[d0], 1);
        int p1 = (d1 >= 0) ? atomicAdd(&cur[d1], 1) : 0;
        int p2 = (d2 >= 0) ? atomicAdd(&cur[d2], 1) : 0;
        int p3 = (d3 >= 0) ? atomicAdd(&cur[d3], 1) : 0;
        csr_src[offs[d0] + p0] = s0;
        if (d1 >= 0) csr_src[offs[d1] + p1] = s1;
        if (d2 >= 0) csr_src[offs[d2] + p2] = s2;
        if (d3 >= 0) csr_src[offs[d3] + p3] = s3;
    }
}

// ---------------- GEMM: C[n,128](bf16) = dinv[r] * f(A)[n,128] @ W[128,128] ----
// BF16IN=0: A fp32, f=identity. BF16IN=1: A bf16, f = relu(a*ss[c]+ss[128+c]).
template <int BF16IN>
__global__ __launch_bounds__(256) void k_gemm(
        const void* __restrict__ Av, const float* __restrict__ W,
        const float* __restrict__ ss, const float* __restrict__ dinv,
        ushort* __restrict__ C, int n) {
    __shared__ float sW[128 * 128];   // 64 KB
    __shared__ float sA[64 * 132];    // 33 KB padded
    const int tid = threadIdx.x;

    for (int i = tid; i < 128 * 128 / 4; i += 256)
        ((float4*)sW)[i] = ((const float4*)W)[i];

    const int rowBase = blockIdx.x * 64;
    if (BF16IN) {
        const uint* A = (const uint*)Av;    // 64 uints per row
        for (int i = tid; i < 1024; i += 256) {         // 64 rows * 16 uint4
            int r = i >> 4, q = i & 15;
            int gr = rowBase + r;
            uint4 u = (gr < n) ? ((const uint4*)A)[(size_t)gr * 16 + q]
                               : make_uint4(0, 0, 0, 0);
            int k = q * 8;
            float f[8] = { bf_lo(u.x), bf_hi(u.x), bf_lo(u.y), bf_hi(u.y),
                           bf_lo(u.z), bf_hi(u.z), bf_lo(u.w), bf_hi(u.w) };
            #pragma unroll
            for (int j = 0; j < 8; j++)
                f[j] = fmaxf(fmaf(f[j], ss[k + j], ss[128 + k + j]), 0.f);
            #pragma unroll
            for (int j = 0; j < 8; j++) sA[r * 132 + k + j] = f[j];
        }
    } else {
        const float* A = (const float*)Av;
        for (int i = tid; i < 2048; i += 256) {         // 64 rows * 32 float4
            int r = i >> 5, k4 = i & 31;
            int gr = rowBase + r;
            float4 v = (gr < n) ? ((const float4*)A)[(size_t)gr * 32 + k4]
                                : make_float4(0.f, 0.f, 0.f, 0.f);
            *(float4*)&sA[r * 132 + k4 * 4] = v;
        }
    }
    __syncthreads();

    const int cgrp = tid & 15, rgrp = tid >> 4;
    const int c0 = cgrp * 4, r0 = rgrp * 4;
    float acc[4][8];
    #pragma unroll
    for (int i = 0; i < 4; i++)
        #pragma unroll
        for (int j = 0; j < 8; j++) acc[i][j] = 0.f;

    for (int k = 0; k < 128; k += 4) {
        float av[4][4];
        #pragma unroll
        for (int i = 0; i < 4; i++) {
            float4 t = *(const float4*)&sA[(r0 + i) * 132 + k];
            av[i][0] = t.x; av[i][1] = t.y; av[i][2] = t.z; av[i][3] = t.w;
        }
        #pragma unroll
        for (int j = 0; j < 4; j++) {
            float4 w0 = *(const float4*)&sW[(k + j) * 128 + c0];
            float4 w1 = *(const float4*)&sW[(k + j) * 128 + 64 + c0];
            #pragma unroll
            for (int i = 0; i < 4; i++) {
                float a = av[i][j];
                acc[i][0] = fmaf(a, w0.x, acc[i][0]);
                acc[i][1] = fmaf(a, w0.y, acc[i][1]);
                acc[i][2] = fmaf(a, w0.z, acc[i][2]);
                acc[i][3] = fmaf(a, w0.w, acc[i][3]);
                acc[i][4] = fmaf(a, w1.x, acc[i][4]);
                acc[i][5] = fmaf(a, w1.y, acc[i][5]);
                acc[i][6] = fmaf(a, w1.z, acc[i][6]);
                acc[i][7] = fmaf(a, w1.w, acc[i][7]);
            }
        }
    }

    #pragma unroll
    for (int i = 0; i < 4; i++) {
        int gr = rowBase + r0 + i;
        if (gr < n) {
            float s = dinv[gr];                 // prescale for the gather
            uint2 lo, hi;
            lo.x = (uint)f2bf(acc[i][0] * s) | ((uint)f2bf(acc[i][1] * s) << 16);
            lo.y = (uint)f2bf(acc[i][2] * s) | ((uint)f2bf(acc[i][3] * s) << 16);
            hi.x = (uint)f2bf(acc[i][4] * s) | ((uint)f2bf(acc[i][5] * s) << 16);
            hi.y = (uint)f2bf(acc[i][6] * s) | ((uint)f2bf(acc[i][7] * s) << 16);
            *(uint2*)&C[(size_t)gr * 128 + c0]      = lo;
            *(uint2*)&C[(size_t)gr * 128 + 64 + c0] = hi;
        }
    }
}

// ---------------- gather-aggregate (one wave per node, bf16 rows) ----------
// hs rows are prescaled by dinv[src]; out[d] = di*(sum hs[src] + hs[d]) + bias
__global__ __launch_bounds__(256) void k_gather(
        const uint* __restrict__ hs, const int* __restrict__ offs,
        const int* __restrict__ csr_src, const float* __restrict__ dinv,
        const float* __restrict__ bias, uint* __restrict__ out, int n) {
    int node = (blockIdx.x * blockDim.x + threadIdx.x) >> 6;
    int lane = threadIdx.x & 63;
    if (node >= n) return;
    const float di = dinv[node];
    const int beg = offs[node], end = offs[node + 1];
    const int c = lane * 2;

    uint hv = hs[(size_t)node * 64 + lane];
    float ax = bf_lo(hv), ay = bf_hi(hv);       // self loop (prescaled)

    int e = beg;
    for (; e + 4 <= end; e += 4) {
        int s0 = csr_src[e + 0], s1 = csr_src[e + 1], s2 = csr_src[e + 2], s3 = csr_src[e + 3];
        uint v0 = hs[(size_t)s0 * 64 + lane];
        uint v1 = hs[(size_t)s1 * 64 + lane];
        uint v2 = hs[(size_t)s2 * 64 + lane];
        uint v3 = hs[(size_t)s3 * 64 + lane];
        ax += bf_lo(v0); ay += bf_hi(v0);
        ax += bf_lo(v1); ay += bf_hi(v1);
        ax += bf_lo(v2); ay += bf_hi(v2);
        ax += bf_lo(v3); ay += bf_hi(v3);
    }
    for (; e < end; ++e) {
        int s = csr_src[e];
        uint v = hs[(size_t)s * 64 + lane];
        ax += bf_lo(v); ay += bf_hi(v);
    }
    float ox = fmaf(di, ax, bias[c]);
    float oy = fmaf(di, ay, bias[c + 1]);
    out[(size_t)node * 64 + lane] = (uint)f2bf(ox) | ((uint)f2bf(oy) << 16);
}

// ---------------- BN stats on bf16 buffer ----------------
__global__ void k_stats(const ushort* __restrict__ h, int n, float* __restrict__ sums) {
    int c = threadIdx.x & 127;
    int half = threadIdx.x >> 7;
    float s = 0.f, s2 = 0.f;
    for (int r = blockIdx.x * 2 + half; r < n; r += gridDim.x * 2) {
        float v = __uint_as_float(((uint)h[(size_t)r * 128 + c]) << 16);
        s += v; s2 = fmaf(v, v, s2);
    }
    __shared__ float sh[256], sh2[256];
    sh[threadIdx.x] = s; sh2[threadIdx.x] = s2;
    __syncthreads();
    if (half == 0) {
        atomicAdd(&sums[c],       s  + sh[threadIdx.x + 128]);
        atomicAdd(&sums[128 + c], s2 + sh2[threadIdx.x + 128]);
    }
}

__global__ void k_bnparam(const float* __restrict__ sums, const float* __restrict__ g,
                          const float* __restrict__ be, int n, float* __restrict__ ss) {
    int c = threadIdx.x;
    float invn = 1.f / (float)n;
    float mean = sums[c] * invn;
    float var = sums[128 + c] * invn - mean * mean;
    float inv = rsqrtf(var + 1e-5f);
    float sc = g[c] * inv;
    ss[c] = sc;
    ss[128 + c] = be[c] - mean * sc;
}

// ---------------- head ----------------
__global__ __launch_bounds__(256) void k_final(
        const uint* __restrict__ h, const float* __restrict__ ss,
        const float* __restrict__ Wl, const float* __restrict__ bl,
        float* __restrict__ out, int n) {
    int node = (blockIdx.x * blockDim.x + threadIdx.x) >> 6;
    int lane = threadIdx.x & 63;
    if (node >= n) return;
    int c = lane * 2;
    uint v = h[(size_t)node * 64 + lane];
    float a0 = fmaxf(fmaf(bf_lo(v), ss[c],     ss[128 + c]),     0.f);
    float a1 = fmaxf(fmaf(bf_hi(v), ss[c + 1], ss[128 + c + 1]), 0.f);
    float p = a0 * Wl[c] + a1 * Wl[c + 1];
    #pragma unroll
    for (int o = 32; o; o >>= 1) p += __shfl_xor(p, o);
    if (lane == 0) {
        float z = fmaxf(p + bl[0], 0.f);
        out[node] = 1.f / (1.f + expf(-z));
    }
}

extern "C" void kernel_launch(void* const* d_in, const int* in_sizes, int n_in,
                              void* d_out, int out_size, void* d_ws, size_t ws_size,
                              hipStream_t stream) {
    const float* x   = (const float*)d_in[0];
    const int*   ei  = (const int*)d_in[1];
    const float* W1  = (const float*)d_in[2];
    const float* b1  = (const float*)d_in[3];
    const float* g1  = (const float*)d_in[4];
    const float* be1 = (const float*)d_in[5];
    const float* W2  = (const float*)d_in[6];
    const float* b2  = (const float*)d_in[7];
    const float* g2  = (const float*)d_in[8];
    const float* be2 = (const float*)d_in[9];
    const float* Wl  = (const float*)d_in[10];
    const float* bl  = (const float*)d_in[11];

    const int N = in_sizes[0] / 128;
    const int E = in_sizes[1] / 2;
    const int* src  = ei;
    const int* dstp = ei + E;

    const int NB = (N + 1023) / 1024;

    char* ws = (char*)d_ws;
    size_t off = 0;
    auto alloc = [&](size_t bytes) {
        void* p = ws + off;
        off += (bytes + 255) & ~(size_t)255;
        return p;
    };
    int*    cnt  = (int*)   alloc((size_t)N * 4);
    float*  dinv = (float*) alloc((size_t)N * 4);
    int*    offs = (int*)   alloc((size_t)(N + 1) * 4);
    int*    cur  = (int*)   alloc((size_t)N * 4);
    int*    bsum = (int*)   alloc((size_t)NB * 4);
    int*    csr  = (int*)   alloc((size_t)E * 4);
    float*  sums = (float*) alloc(512 * 4);
    float*  ss   = (float*) alloc(512 * 4);
    ushort* hbuf = (ushort*)alloc((size_t)N * 128 * 2);   // bf16
    ushort* abuf = (ushort*)alloc((size_t)N * 128 * 2);   // bf16

    hipMemsetAsync(cnt,  0, (size_t)N * 4, stream);
    hipMemsetAsync(cur,  0, (size_t)N * 4, stream);
    hipMemsetAsync(sums, 0, 512 * 4, stream);

    // graph structure
    k_deg       <<<2048, 256, 0, stream>>>(dstp, E, cnt);
    k_dinv      <<<(N + 255) / 256, 256, 0, stream>>>(cnt, dinv, N);
    k_scan_local<<<NB, 256, 0, stream>>>(cnt, N, offs, bsum);
    k_scan_bsum <<<1, 1024, 0, stream>>>(bsum, NB, offs + N);
    k_scan_add  <<<NB, 256, 0, stream>>>(offs, N, bsum);
    k_fill      <<<2048, 256, 0, stream>>>(src, dstp, E, offs, cur, csr);

    // layer 1
    k_gemm<0> <<<(N + 63) / 64, 256, 0, stream>>>(x, W1, nullptr, dinv, hbuf, N);
    k_gather  <<<(N + 3) / 4, 256, 0, stream>>>((const uint*)hbuf, offs, csr, dinv, b1, (uint*)abuf, N);
    k_stats   <<<512, 256, 0, stream>>>(abuf, N, sums);
    k_bnparam <<<1, 128, 0, stream>>>(sums, g1, be1, N, ss);

    // layer 2 (BN1+ReLU fused into GEMM2's A-load)
    k_gemm<1> <<<(N + 63) / 64, 256, 0, stream>>>(abuf, W2, ss, dinv, hbuf, N);
    k_gather  <<<(N + 3) / 4, 256, 0, stream>>>((const uint*)hbuf, offs, csr, dinv, b2, (uint*)abuf, N);
    k_stats   <<<512, 256, 0, stream>>>(abuf, N, sums + 256);
    k_bnparam <<<1, 128, 0, stream>>>(sums + 256, g2, be2, N, ss + 256);

    // head (BN2+ReLU fused)
    k_final<<<(N + 3) / 4, 256, 0, stream>>>((const uint*)abuf, ss + 256, Wl, bl, (float*)d_out, N);
}

// Round 4
// 430.427 us; speedup vs baseline: 2.0199x; 1.4538x over previous
//
#include <hip/hip_runtime.h>
#include <cstdint>
#include <cstddef>

typedef unsigned int uint;
typedef unsigned short ushort;
typedef __attribute__((ext_vector_type(8))) short bf16x8;
typedef __attribute__((ext_vector_type(4))) float f32x4;

__device__ __forceinline__ ushort f2bf(float f) {          // RNE float->bf16
    uint b = __float_as_uint(f);
    return (ushort)((b + 0x7FFF + ((b >> 16) & 1)) >> 16);
}
__device__ __forceinline__ float bf_lo(uint u) { return __uint_as_float(u << 16); }
__device__ __forceinline__ float bf_hi(uint u) { return __uint_as_float(u & 0xFFFF0000u); }

// ---------------- degree count + slot assignment (ILP x4) ----------------
__global__ void k_deg(const int* __restrict__ dst, int E,
                      int* __restrict__ cnt, int* __restrict__ pos) {
    const int T = gridDim.x * blockDim.x;
    for (int i = blockIdx.x * blockDim.x + threadIdx.x; i < E; i += 4 * T) {
        int i1 = i + T, i2 = i + 2 * T, i3 = i + 3 * T;
        int d0 = dst[i];
        int d1 = (i1 < E) ? dst[i1] : -1;
        int d2 = (i2 < E) ? dst[i2] : -1;
        int d3 = (i3 < E) ? dst[i3] : -1;
        int p0 = atomicAdd(&cnt[d0], 1);
        int p1 = (d1 >= 0) ? atomicAdd(&cnt[d1], 1) : 0;
        int p2 = (d2 >= 0) ? atomicAdd(&cnt[d2], 1) : 0;
        int p3 = (d3 >= 0) ? atomicAdd(&cnt[d3], 1) : 0;
        pos[i] = p0;
        if (d1 >= 0) pos[i1] = p1;
        if (d2 >= 0) pos[i2] = p2;
        if (d3 >= 0) pos[i3] = p3;
    }
}

// dinv[i] = rsqrt(indeg + 1)
__global__ void k_dinv(const int* __restrict__ cnt, float* __restrict__ dinv, int n) {
    int i = blockIdx.x * blockDim.x + threadIdx.x;
    if (i < n) dinv[i] = rsqrtf((float)(cnt[i] + 1));
}

// ---------------- hierarchical exclusive scan ----------------
__global__ __launch_bounds__(256) void k_scan_local(
        const int* __restrict__ cnt, int n,
        int* __restrict__ offs, int* __restrict__ bsum) {
    __shared__ int sh[256];
    const int base = blockIdx.x * 1024 + threadIdx.x * 4;
    int v[4];
    #pragma unroll
    for (int j = 0; j < 4; j++) { int g = base + j; v[j] = (g < n) ? cnt[g] : 0; }
    const int tsum = v[0] + v[1] + v[2] + v[3];
    sh[threadIdx.x] = tsum;
    __syncthreads();
    #pragma unroll
    for (int o = 1; o < 256; o <<= 1) {
        int t = (threadIdx.x >= (unsigned)o) ? sh[threadIdx.x - o] : 0;
        __syncthreads();
        sh[threadIdx.x] += t;
        __syncthreads();
    }
    int run = sh[threadIdx.x] - tsum;
    #pragma unroll
    for (int j = 0; j < 4; j++) {
        int g = base + j;
        if (g < n) offs[g] = run;
        run += v[j];
    }
    if (threadIdx.x == 255) bsum[blockIdx.x] = sh[255];
}

__global__ __launch_bounds__(1024) void k_scan_bsum(
        int* __restrict__ bsum, int nb, int* __restrict__ total) {
    __shared__ int sh[1024];
    const int t = threadIdx.x;
    int v = (t < nb) ? bsum[t] : 0;
    sh[t] = v;
    __syncthreads();
    #pragma unroll
    for (int o = 1; o < 1024; o <<= 1) {
        int x = (t >= (unsigned)o) ? sh[t - o] : 0;
        __syncthreads();
        sh[t] += x;
        __syncthreads();
    }
    if (t < nb) bsum[t] = sh[t] - v;
    if (t == 1023) *total = sh[1023];
}

__global__ __launch_bounds__(256) void k_scan_add(
        int* __restrict__ offs, int n, const int* __restrict__ bsum) {
    const int add = bsum[blockIdx.x];
    const int base = blockIdx.x * 1024;
    #pragma unroll
    for (int j = 0; j < 4; j++) {
        int g = base + threadIdx.x + j * 256;
        if (g < n) offs[g] += add;
    }
}

// ---------------- CSR fill — atomic-free (slots precomputed) ----------------
__global__ void k_fill(const int* __restrict__ src, const int* __restrict__ dst,
                       const int* __restrict__ pos, int E,
                       const int* __restrict__ offs, int* __restrict__ csr_src) {
    const int T = gridDim.x * blockDim.x;
    for (int i = blockIdx.x * blockDim.x + threadIdx.x; i < E; i += 2 * T) {
        int i1 = i + T;
        int d0 = dst[i], s0 = src[i], p0 = pos[i];
        int d1 = -1, s1 = 0, p1 = 0;
        if (i1 < E) { d1 = dst[i1]; s1 = src[i1]; p1 = pos[i1]; }
        int o0 = offs[d0];
        int o1 = (d1 >= 0) ? offs[d1] : 0;
        csr_src[o0 + p0] = s0;
        if (d1 >= 0) csr_src[o1 + p1] = s1;
    }
}

// ---------------- W transpose + bf16 convert: WT[n][k] = bf16(W[k][n]) -------
__global__ void k_wprep(const float* __restrict__ W, ushort* __restrict__ WT) {
    int idx = blockIdx.x * 256 + threadIdx.x;   // 16384 total
    int n = idx >> 7, k = idx & 127;
    WT[idx] = f2bf(W[k * 128 + n]);
}

// ---------------- MFMA GEMM: C[n,128](bf16) = dinv[r] * f(A) @ W -------------
// LAYER 0: A fp32, f = identity.  LAYER 1: A bf16, f = relu(a*ss[k]+ss[128+k]).
// One wave computes a 16-row x 128-col strip. No LDS.
template <int LAYER>
__global__ __launch_bounds__(256) void k_gemm(
        const void* __restrict__ Av, const ushort* __restrict__ WT,
        const float* __restrict__ ss, const float* __restrict__ dinv,
        ushort* __restrict__ C, int n) {
    const int lane = threadIdx.x & 63;
    const int wid  = threadIdx.x >> 6;
    const int m0   = blockIdx.x * 64 + wid * 16;
    const int lm   = lane & 15;          // A row / B col within tile
    const int lq   = lane >> 4;          // k-subgroup 0..3
    const int row  = m0 + lm;
    const bool rv  = row < n;

    f32x4 acc[8];
    #pragma unroll
    for (int i = 0; i < 8; i++) acc[i] = (f32x4){0.f, 0.f, 0.f, 0.f};

    #pragma unroll
    for (int ks = 0; ks < 4; ks++) {
        const int kb = ks * 32 + lq * 8;
        bf16x8 af;
        if (LAYER == 0) {
            const float* A = (const float*)Av;
            float4 v0, v1;
            if (rv) {
                v0 = *(const float4*)&A[(size_t)row * 128 + kb];
                v1 = *(const float4*)&A[(size_t)row * 128 + kb + 4];
            } else {
                v0 = make_float4(0.f, 0.f, 0.f, 0.f);
                v1 = v0;
            }
            af[0] = (short)f2bf(v0.x); af[1] = (short)f2bf(v0.y);
            af[2] = (short)f2bf(v0.z); af[3] = (short)f2bf(v0.w);
            af[4] = (short)f2bf(v1.x); af[5] = (short)f2bf(v1.y);
            af[6] = (short)f2bf(v1.z); af[7] = (short)f2bf(v1.w);
        } else {
            const uint* A = (const uint*)Av;
            uint4 u = rv ? *(const uint4*)&A[(size_t)row * 64 + kb / 2]
                         : make_uint4(0, 0, 0, 0);
            float4 sc0 = *(const float4*)&ss[kb];
            float4 sc1 = *(const float4*)&ss[kb + 4];
            float4 sh0 = *(const float4*)&ss[128 + kb];
            float4 sh1 = *(const float4*)&ss[128 + kb + 4];
            float f0 = fmaxf(fmaf(bf_lo(u.x), sc0.x, sh0.x), 0.f);
            float f1 = fmaxf(fmaf(bf_hi(u.x), sc0.y, sh0.y), 0.f);
            float f2 = fmaxf(fmaf(bf_lo(u.y), sc0.z, sh0.z), 0.f);
            float f3 = fmaxf(fmaf(bf_hi(u.y), sc0.w, sh0.w), 0.f);
            float f4 = fmaxf(fmaf(bf_lo(u.z), sc1.x, sh1.x), 0.f);
            float f5 = fmaxf(fmaf(bf_hi(u.z), sc1.y, sh1.y), 0.f);
            float f6 = fmaxf(fmaf(bf_lo(u.w), sc1.z, sh1.z), 0.f);
            float f7 = fmaxf(fmaf(bf_hi(u.w), sc1.w, sh1.w), 0.f);
            af[0] = (short)f2bf(f0); af[1] = (short)f2bf(f1);
            af[2] = (short)f2bf(f2); af[3] = (short)f2bf(f3);
            af[4] = (short)f2bf(f4); af[5] = (short)f2bf(f5);
            af[6] = (short)f2bf(f6); af[7] = (short)f2bf(f7);
        }
        #pragma unroll
        for (int nt = 0; nt < 8; nt++) {
            bf16x8 bfr = *(const bf16x8*)&WT[(size_t)(nt * 16 + lm) * 128 + kb];
            acc[nt] = __builtin_amdgcn_mfma_f32_16x16x32_bf16(af, bfr, acc[nt], 0, 0, 0);
        }
    }

    // C/D layout: col = lane&15, row = (lane>>4)*4 + reg
    const int orow0 = m0 + lq * 4;
    #pragma unroll
    for (int r = 0; r < 4; r++) {
        const int orow = orow0 + r;
        if (orow < n) {
            const float s = dinv[orow];   // prescale for the gather
            #pragma unroll
            for (int nt = 0; nt < 8; nt++)
                C[(size_t)orow * 128 + nt * 16 + lm] = f2bf(acc[nt][r] * s);
        }
    }
}

// ---------------- gather-aggregate (one wave per node, bf16 rows) ----------
__global__ __launch_bounds__(256) void k_gather(
        const uint* __restrict__ hs, const int* __restrict__ offs,
        const int* __restrict__ csr_src, const float* __restrict__ dinv,
        const float* __restrict__ bias, uint* __restrict__ out, int n) {
    int node = (blockIdx.x * blockDim.x + threadIdx.x) >> 6;
    int lane = threadIdx.x & 63;
    if (node >= n) return;
    const float di = dinv[node];
    const int beg = offs[node], end = offs[node + 1];
    const int c = lane * 2;

    uint hv = hs[(size_t)node * 64 + lane];
    float ax = bf_lo(hv), ay = bf_hi(hv);       // self loop (prescaled)

    int e = beg;
    for (; e + 4 <= end; e += 4) {
        int s0 = csr_src[e + 0], s1 = csr_src[e + 1], s2 = csr_src[e + 2], s3 = csr_src[e + 3];
        uint v0 = hs[(size_t)s0 * 64 + lane];
        uint v1 = hs[(size_t)s1 * 64 + lane];
        uint v2 = hs[(size_t)s2 * 64 + lane];
        uint v3 = hs[(size_t)s3 * 64 + lane];
        ax += bf_lo(v0); ay += bf_hi(v0);
        ax += bf_lo(v1); ay += bf_hi(v1);
        ax += bf_lo(v2); ay += bf_hi(v2);
        ax += bf_lo(v3); ay += bf_hi(v3);
    }
    for (; e < end; ++e) {
        int s = csr_src[e];
        uint v = hs[(size_t)s * 64 + lane];
        ax += bf_lo(v); ay += bf_hi(v);
    }
    float ox = fmaf(di, ax, bias[c]);
    float oy = fmaf(di, ay, bias[c + 1]);
    out[(size_t)node * 64 + lane] = (uint)f2bf(ox) | ((uint)f2bf(oy) << 16);
}

// ---------------- BN stats (packed uint loads) ----------------
__global__ __launch_bounds__(256) void k_stats(
        const uint* __restrict__ h, int n, float* __restrict__ sums) {
    const int j   = threadIdx.x & 63;      // uint (feature-pair) index
    const int sub = threadIdx.x >> 6;      // 0..3 row slots
    float slo = 0.f, s2lo = 0.f, shi = 0.f, s2hi = 0.f;
    for (int r = blockIdx.x * 4 + sub; r < n; r += gridDim.x * 4) {
        uint u = h[(size_t)r * 64 + j];
        float a = bf_lo(u), b = bf_hi(u);
        slo += a; s2lo = fmaf(a, a, s2lo);
        shi += b; s2hi = fmaf(b, b, s2hi);
    }
    __shared__ float sh[4][256];
    sh[0][threadIdx.x] = slo; sh[1][threadIdx.x] = s2lo;
    sh[2][threadIdx.x] = shi; sh[3][threadIdx.x] = s2hi;
    __syncthreads();
    if (sub == 0) {
        float a0 = 0.f, a1 = 0.f, a2 = 0.f, a3 = 0.f;
        #pragma unroll
        for (int t = 0; t < 4; t++) {
            a0 += sh[0][t * 64 + j]; a1 += sh[1][t * 64 + j];
            a2 += sh[2][t * 64 + j]; a3 += sh[3][t * 64 + j];
        }
        atomicAdd(&sums[2 * j],           a0);
        atomicAdd(&sums[128 + 2 * j],     a1);
        atomicAdd(&sums[2 * j + 1],       a2);
        atomicAdd(&sums[128 + 2 * j + 1], a3);
    }
}

__global__ void k_bnparam(const float* __restrict__ sums, const float* __restrict__ g,
                          const float* __restrict__ be, int n, float* __restrict__ ss) {
    int c = threadIdx.x;
    float invn = 1.f / (float)n;
    float mean = sums[c] * invn;
    float var = sums[128 + c] * invn - mean * mean;
    float inv = rsqrtf(var + 1e-5f);
    float sc = g[c] * inv;
    ss[c] = sc;
    ss[128 + c] = be[c] - mean * sc;
}

// ---------------- head ----------------
__global__ __launch_bounds__(256) void k_final(
        const uint* __restrict__ h, const float* __restrict__ ss,
        const float* __restrict__ Wl, const float* __restrict__ bl,
        float* __restrict__ out, int n) {
    int node = (blockIdx.x * blockDim.x + threadIdx.x) >> 6;
    int lane = threadIdx.x & 63;
    if (node >= n) return;
    int c = lane * 2;
    uint v = h[(size_t)node * 64 + lane];
    float a0 = fmaxf(fmaf(bf_lo(v), ss[c],     ss[128 + c]),     0.f);
    float a1 = fmaxf(fmaf(bf_hi(v), ss[c + 1], ss[128 + c + 1]), 0.f);
    float p = a0 * Wl[c] + a1 * Wl[c + 1];
    #pragma unroll
    for (int o = 32; o; o >>= 1) p += __shfl_xor(p, o);
    if (lane == 0) {
        float z = fmaxf(p + bl[0], 0.f);
        out[node] = 1.f / (1.f + expf(-z));
    }
}

extern "C" void kernel_launch(void* const* d_in, const int* in_sizes, int n_in,
                              void* d_out, int out_size, void* d_ws, size_t ws_size,
                              hipStream_t stream) {
    const float* x   = (const float*)d_in[0];
    const int*   ei  = (const int*)d_in[1];
    const float* W1  = (const float*)d_in[2];
    const float* b1  = (const float*)d_in[3];
    const float* g1  = (const float*)d_in[4];
    const float* be1 = (const float*)d_in[5];
    const float* W2  = (const float*)d_in[6];
    const float* b2  = (const float*)d_in[7];
    const float* g2  = (const float*)d_in[8];
    const float* be2 = (const float*)d_in[9];
    const float* Wl  = (const float*)d_in[10];
    const float* bl  = (const float*)d_in[11];

    const int N = in_sizes[0] / 128;
    const int E = in_sizes[1] / 2;
    const int* src  = ei;
    const int* dstp = ei + E;

    const int NB = (N + 1023) / 1024;

    char* ws = (char*)d_ws;
    size_t off = 0;
    auto alloc = [&](size_t bytes) {
        void* p = ws + off;
        off += (bytes + 255) & ~(size_t)255;
        return p;
    };
    int*    cnt  = (int*)   alloc((size_t)N * 4);
    float*  dinv = (float*) alloc((size_t)N * 4);
    int*    offs = (int*)   alloc((size_t)(N + 1) * 4);
    int*    pos  = (int*)   alloc((size_t)E * 4);
    int*    bsum = (int*)   alloc((size_t)NB * 4);
    int*    csr  = (int*)   alloc((size_t)E * 4);
    float*  sums = (float*) alloc(512 * 4);
    float*  ss   = (float*) alloc(512 * 4);
    ushort* WT1  = (ushort*)alloc(128 * 128 * 2);
    ushort* WT2  = (ushort*)alloc(128 * 128 * 2);
    ushort* hbuf = (ushort*)alloc((size_t)N * 128 * 2);
    ushort* abuf = (ushort*)alloc((size_t)N * 128 * 2);

    hipMemsetAsync(cnt,  0, (size_t)N * 4, stream);
    hipMemsetAsync(sums, 0, 512 * 4, stream);

    // graph structure
    k_deg       <<<2048, 256, 0, stream>>>(dstp, E, cnt, pos);
    k_dinv      <<<(N + 255) / 256, 256, 0, stream>>>(cnt, dinv, N);
    k_scan_local<<<NB, 256, 0, stream>>>(cnt, N, offs, bsum);
    k_scan_bsum <<<1, 1024, 0, stream>>>(bsum, NB, offs + N);
    k_scan_add  <<<NB, 256, 0, stream>>>(offs, N, bsum);
    k_fill      <<<2048, 256, 0, stream>>>(src, dstp, pos, E, offs, csr);

    // weight prep
    k_wprep<<<64, 256, 0, stream>>>(W1, WT1);
    k_wprep<<<64, 256, 0, stream>>>(W2, WT2);

    // layer 1
    k_gemm<0> <<<(N + 63) / 64, 256, 0, stream>>>(x, WT1, nullptr, dinv, hbuf, N);
    k_gather  <<<(N + 3) / 4, 256, 0, stream>>>((const uint*)hbuf, offs, csr, dinv, b1, (uint*)abuf, N);
    k_stats   <<<512, 256, 0, stream>>>((const uint*)abuf, N, sums);
    k_bnparam <<<1, 128, 0, stream>>>(sums, g1, be1, N, ss);

    // layer 2 (BN1+ReLU fused into GEMM2's A-frag load)
    k_gemm<1> <<<(N + 63) / 64, 256, 0, stream>>>(abuf, WT2, ss, dinv, hbuf, N);
    k_gather  <<<(N + 3) / 4, 256, 0, stream>>>((const uint*)hbuf, offs, csr, dinv, b2, (uint*)abuf, N);
    k_stats   <<<512, 256, 0, stream>>>((const uint*)abuf, N, sums + 256);
    k_bnparam <<<1, 128, 0, stream>>>(sums + 256, g2, be2, N, ss + 256);

    // head (BN2+ReLU fused)
    k_final<<<(N + 3) / 4, 256, 0, stream>>>((const uint*)abuf, ss + 256, Wl, bl, (float*)d_out, N);
}

// Round 5
// 373.434 us; speedup vs baseline: 2.3282x; 1.1526x over previous
//
#include <hip/hip_runtime.h>
#include <cstdint>
#include <cstddef>

typedef unsigned int uint;
typedef unsigned short ushort;
typedef __attribute__((ext_vector_type(8))) short bf16x8;
typedef __attribute__((ext_vector_type(4))) float f32x4;

__device__ __forceinline__ ushort f2bf(float f) {          // RNE float->bf16
    uint b = __float_as_uint(f);
    return (ushort)((b + 0x7FFF + ((b >> 16) & 1)) >> 16);
}
__device__ __forceinline__ float bf_lo(uint u) { return __uint_as_float(u << 16); }
__device__ __forceinline__ float bf_hi(uint u) { return __uint_as_float(u & 0xFFFF0000u); }

// ============ CSR build via bucketed counting sort (no global atomics) ======
// bucket b = dst >> 8 (256 nodes per bucket). NBKT <= 512 assumed (N <= 128K).

// P1: per-block coarse histogram -> cnt2d[b*256 + blk]
__global__ __launch_bounds__(256) void k_bcount(
        const int* __restrict__ dst, int E, int chunk,
        int* __restrict__ cnt2d, int nbkt) {
    __shared__ int hist[512];
    for (int b = threadIdx.x; b < nbkt; b += 256) hist[b] = 0;
    __syncthreads();
    const int beg = blockIdx.x * chunk;
    const int end = min(beg + chunk, E);
    for (int i = beg + threadIdx.x; i < end; i += 256)
        atomicAdd(&hist[dst[i] >> 8], 1);
    __syncthreads();
    for (int b = threadIdx.x; b < nbkt; b += 256)
        cnt2d[b * 256 + blockIdx.x] = hist[b];
}

// P2: scatter packed edges into per-(bucket,block) slices (sequential writes)
__global__ __launch_bounds__(256) void k_bscatter(
        const int* __restrict__ src, const int* __restrict__ dst, int E, int chunk,
        const int* __restrict__ cnt2dx, uint* __restrict__ ebuf, int nbkt) {
    __shared__ int lcur[512];
    for (int b = threadIdx.x; b < nbkt; b += 256)
        lcur[b] = cnt2dx[b * 256 + blockIdx.x];
    __syncthreads();
    const int beg = blockIdx.x * chunk;
    const int end = min(beg + chunk, E);
    for (int i = beg + threadIdx.x; i < end; i += 256) {
        int d = dst[i];
        int s = src[i];
        int slot = atomicAdd(&lcur[d >> 8], 1);     // LDS atomic
        ebuf[slot] = ((uint)(d & 255) << 17) | (uint)s;
    }
}

// P3: one block per bucket: fine counts -> cnt, offs, and grouped csr
__global__ __launch_bounds__(256) void k_bcsr(
        const uint* __restrict__ ebuf, const int* __restrict__ cnt2dx,
        int E, int n, int nbkt,
        int* __restrict__ cnt, int* __restrict__ offs, int* __restrict__ csr) {
    __shared__ int fine[256], finex[256], fcur[256];
    const int b = blockIdx.x;
    const int t = threadIdx.x;
    const int ebeg = cnt2dx[b * 256];
    const int eend = (b + 1 < nbkt) ? cnt2dx[(b + 1) * 256] : E;
    fine[t] = 0;
    __syncthreads();
    for (int i = ebeg + t; i < eend; i += 256)
        atomicAdd(&fine[ebuf[i] >> 17], 1);
    __syncthreads();
    const int node = b * 256 + t;
    if (node < n) cnt[node] = fine[t];
    int v = fine[t];
    finex[t] = v;
    __syncthreads();
    #pragma unroll
    for (int o = 1; o < 256; o <<= 1) {
        int x = (t >= o) ? finex[t - o] : 0;
        __syncthreads();
        finex[t] += x;
        __syncthreads();
    }
    const int ex = finex[t] - v;                    // exclusive prefix
    fcur[t] = ex;
    if (node <= n) offs[node] = ebeg + ex;
    if (b == 0 && t == 0) offs[n] = E;
    __syncthreads();
    for (int i = ebeg + t; i < eend; i += 256) {
        uint e = ebuf[i];
        int f = (int)(e >> 17);
        int p = atomicAdd(&fcur[f], 1);             // LDS atomic
        csr[ebeg + p] = (int)(e & 0x1FFFF);
    }
}

// dinv[i] = rsqrt(indeg + 1)
__global__ void k_dinv(const int* __restrict__ cnt, float* __restrict__ dinv, int n) {
    int i = blockIdx.x * blockDim.x + threadIdx.x;
    if (i < n) dinv[i] = rsqrtf((float)(cnt[i] + 1));
}

// ---------------- hierarchical exclusive scan (used on cnt2d) --------------
__global__ __launch_bounds__(256) void k_scan_local(
        const int* __restrict__ cnt, int n,
        int* __restrict__ offs, int* __restrict__ bsum) {
    __shared__ int sh[256];
    const int base = blockIdx.x * 1024 + threadIdx.x * 4;
    int v[4];
    #pragma unroll
    for (int j = 0; j < 4; j++) { int g = base + j; v[j] = (g < n) ? cnt[g] : 0; }
    const int tsum = v[0] + v[1] + v[2] + v[3];
    sh[threadIdx.x] = tsum;
    __syncthreads();
    #pragma unroll
    for (int o = 1; o < 256; o <<= 1) {
        int t = (threadIdx.x >= (unsigned)o) ? sh[threadIdx.x - o] : 0;
        __syncthreads();
        sh[threadIdx.x] += t;
        __syncthreads();
    }
    int run = sh[threadIdx.x] - tsum;
    #pragma unroll
    for (int j = 0; j < 4; j++) {
        int g = base + j;
        if (g < n) offs[g] = run;
        run += v[j];
    }
    if (threadIdx.x == 255) bsum[blockIdx.x] = sh[255];
}

__global__ __launch_bounds__(1024) void k_scan_bsum(
        int* __restrict__ bsum, int nb, int* __restrict__ total) {
    __shared__ int sh[1024];
    const int t = threadIdx.x;
    int v = (t < nb) ? bsum[t] : 0;
    sh[t] = v;
    __syncthreads();
    #pragma unroll
    for (int o = 1; o < 1024; o <<= 1) {
        int x = (t >= (unsigned)o) ? sh[t - o] : 0;
        __syncthreads();
        sh[t] += x;
        __syncthreads();
    }
    if (t < nb) bsum[t] = sh[t] - v;
    if (t == 1023) *total = sh[1023];
}

__global__ __launch_bounds__(256) void k_scan_add(
        int* __restrict__ offs, int n, const int* __restrict__ bsum) {
    const int add = bsum[blockIdx.x];
    const int base = blockIdx.x * 1024;
    #pragma unroll
    for (int j = 0; j < 4; j++) {
        int g = base + threadIdx.x + j * 256;
        if (g < n) offs[g] += add;
    }
}

// ---------------- W transpose + bf16 convert: WT[n][k] = bf16(W[k][n]) -------
__global__ void k_wprep(const float* __restrict__ W, ushort* __restrict__ WT) {
    int idx = blockIdx.x * 256 + threadIdx.x;   // 16384 total
    int n = idx >> 7, k = idx & 127;
    WT[idx] = f2bf(W[k * 128 + n]);
}

// ---------------- MFMA GEMM: C[n,128](bf16) = dinv[r] * f(A) @ W -------------
template <int LAYER>
__global__ __launch_bounds__(256) void k_gemm(
        const void* __restrict__ Av, const ushort* __restrict__ WT,
        const float* __restrict__ ss, const float* __restrict__ dinv,
        ushort* __restrict__ C, int n) {
    const int lane = threadIdx.x & 63;
    const int wid  = threadIdx.x >> 6;
    const int m0   = blockIdx.x * 64 + wid * 16;
    const int lm   = lane & 15;
    const int lq   = lane >> 4;
    const int row  = m0 + lm;
    const bool rv  = row < n;

    f32x4 acc[8];
    #pragma unroll
    for (int i = 0; i < 8; i++) acc[i] = (f32x4){0.f, 0.f, 0.f, 0.f};

    #pragma unroll
    for (int ks = 0; ks < 4; ks++) {
        const int kb = ks * 32 + lq * 8;
        bf16x8 af;
        if (LAYER == 0) {
            const float* A = (const float*)Av;
            float4 v0, v1;
            if (rv) {
                v0 = *(const float4*)&A[(size_t)row * 128 + kb];
                v1 = *(const float4*)&A[(size_t)row * 128 + kb + 4];
            } else {
                v0 = make_float4(0.f, 0.f, 0.f, 0.f);
                v1 = v0;
            }
            af[0] = (short)f2bf(v0.x); af[1] = (short)f2bf(v0.y);
            af[2] = (short)f2bf(v0.z); af[3] = (short)f2bf(v0.w);
            af[4] = (short)f2bf(v1.x); af[5] = (short)f2bf(v1.y);
            af[6] = (short)f2bf(v1.z); af[7] = (short)f2bf(v1.w);
        } else {
            const uint* A = (const uint*)Av;
            uint4 u = rv ? *(const uint4*)&A[(size_t)row * 64 + kb / 2]
                         : make_uint4(0, 0, 0, 0);
            float4 sc0 = *(const float4*)&ss[kb];
            float4 sc1 = *(const float4*)&ss[kb + 4];
            float4 sh0 = *(const float4*)&ss[128 + kb];
            float4 sh1 = *(const float4*)&ss[128 + kb + 4];
            float f0 = fmaxf(fmaf(bf_lo(u.x), sc0.x, sh0.x), 0.f);
            float f1 = fmaxf(fmaf(bf_hi(u.x), sc0.y, sh0.y), 0.f);
            float f2 = fmaxf(fmaf(bf_lo(u.y), sc0.z, sh0.z), 0.f);
            float f3 = fmaxf(fmaf(bf_hi(u.y), sc0.w, sh0.w), 0.f);
            float f4 = fmaxf(fmaf(bf_lo(u.z), sc1.x, sh1.x), 0.f);
            float f5 = fmaxf(fmaf(bf_hi(u.z), sc1.y, sh1.y), 0.f);
            float f6 = fmaxf(fmaf(bf_lo(u.w), sc1.z, sh1.z), 0.f);
            float f7 = fmaxf(fmaf(bf_hi(u.w), sc1.w, sh1.w), 0.f);
            af[0] = (short)f2bf(f0); af[1] = (short)f2bf(f1);
            af[2] = (short)f2bf(f2); af[3] = (short)f2bf(f3);
            af[4] = (short)f2bf(f4); af[5] = (short)f2bf(f5);
            af[6] = (short)f2bf(f6); af[7] = (short)f2bf(f7);
        }
        #pragma unroll
        for (int nt = 0; nt < 8; nt++) {
            bf16x8 bfr = *(const bf16x8*)&WT[(size_t)(nt * 16 + lm) * 128 + kb];
            acc[nt] = __builtin_amdgcn_mfma_f32_16x16x32_bf16(af, bfr, acc[nt], 0, 0, 0);
        }
    }

    const int orow0 = m0 + lq * 4;
    #pragma unroll
    for (int r = 0; r < 4; r++) {
        const int orow = orow0 + r;
        if (orow < n) {
            const float s = dinv[orow];
            #pragma unroll
            for (int nt = 0; nt < 8; nt++)
                C[(size_t)orow * 128 + nt * 16 + lm] = f2bf(acc[nt][r] * s);
        }
    }
}

// ---------------- gather-aggregate (one wave per node, 8-deep pipeline) -----
__global__ __launch_bounds__(256) void k_gather(
        const uint* __restrict__ hs, const int* __restrict__ offs,
        const int* __restrict__ csr, const float* __restrict__ dinv,
        const float* __restrict__ bias, uint* __restrict__ out, int n) {
    int node = (blockIdx.x * blockDim.x + threadIdx.x) >> 6;
    int lane = threadIdx.x & 63;
    if (node >= n) return;
    const float di = dinv[node];
    const int beg = offs[node], end = offs[node + 1];
    const int c = lane * 2;

    uint hv = hs[(size_t)node * 64 + lane];
    float ax = bf_lo(hv), ay = bf_hi(hv);       // self loop (prescaled)

    int e = beg;
    if (e + 8 <= end) {
        int idx[8];
        #pragma unroll
        for (int j = 0; j < 8; j++) idx[j] = csr[e + j];
        while (e + 16 <= end) {
            uint v[8];
            #pragma unroll
            for (int j = 0; j < 8; j++) v[j] = hs[(size_t)idx[j] * 64 + lane];
            #pragma unroll
            for (int j = 0; j < 8; j++) idx[j] = csr[e + 8 + j];   // prefetch
            #pragma unroll
            for (int j = 0; j < 8; j++) { ax += bf_lo(v[j]); ay += bf_hi(v[j]); }
            e += 8;
        }
        uint v[8];
        #pragma unroll
        for (int j = 0; j < 8; j++) v[j] = hs[(size_t)idx[j] * 64 + lane];
        #pragma unroll
        for (int j = 0; j < 8; j++) { ax += bf_lo(v[j]); ay += bf_hi(v[j]); }
        e += 8;
    }
    for (; e < end; ++e) {
        uint v = hs[(size_t)csr[e] * 64 + lane];
        ax += bf_lo(v); ay += bf_hi(v);
    }
    float ox = fmaf(di, ax, bias[c]);
    float oy = fmaf(di, ay, bias[c + 1]);
    out[(size_t)node * 64 + lane] = (uint)f2bf(ox) | ((uint)f2bf(oy) << 16);
}

// ---------------- BN stats (packed uint loads) ----------------
__global__ __launch_bounds__(256) void k_stats(
        const uint* __restrict__ h, int n, float* __restrict__ sums) {
    const int j   = threadIdx.x & 63;
    const int sub = threadIdx.x >> 6;
    float slo = 0.f, s2lo = 0.f, shi = 0.f, s2hi = 0.f;
    for (int r = blockIdx.x * 4 + sub; r < n; r += gridDim.x * 4) {
        uint u = h[(size_t)r * 64 + j];
        float a = bf_lo(u), b = bf_hi(u);
        slo += a; s2lo = fmaf(a, a, s2lo);
        shi += b; s2hi = fmaf(b, b, s2hi);
    }
    __shared__ float sh[4][256];
    sh[0][threadIdx.x] = slo; sh[1][threadIdx.x] = s2lo;
    sh[2][threadIdx.x] = shi; sh[3][threadIdx.x] = s2hi;
    __syncthreads();
    if (sub == 0) {
        float a0 = 0.f, a1 = 0.f, a2 = 0.f, a3 = 0.f;
        #pragma unroll
        for (int t = 0; t < 4; t++) {
            a0 += sh[0][t * 64 + j]; a1 += sh[1][t * 64 + j];
            a2 += sh[2][t * 64 + j]; a3 += sh[3][t * 64 + j];
        }
        atomicAdd(&sums[2 * j],           a0);
        atomicAdd(&sums[128 + 2 * j],     a1);
        atomicAdd(&sums[2 * j + 1],       a2);
        atomicAdd(&sums[128 + 2 * j + 1], a3);
    }
}

__global__ void k_bnparam(const float* __restrict__ sums, const float* __restrict__ g,
                          const float* __restrict__ be, int n, float* __restrict__ ss) {
    int c = threadIdx.x;
    float invn = 1.f / (float)n;
    float mean = sums[c] * invn;
    float var = sums[128 + c] * invn - mean * mean;
    float inv = rsqrtf(var + 1e-5f);
    float sc = g[c] * inv;
    ss[c] = sc;
    ss[128 + c] = be[c] - mean * sc;
}

// ---------------- head ----------------
__global__ __launch_bounds__(256) void k_final(
        const uint* __restrict__ h, const float* __restrict__ ss,
        const float* __restrict__ Wl, const float* __restrict__ bl,
        float* __restrict__ out, int n) {
    int node = (blockIdx.x * blockDim.x + threadIdx.x) >> 6;
    int lane = threadIdx.x & 63;
    if (node >= n) return;
    int c = lane * 2;
    uint v = h[(size_t)node * 64 + lane];
    float a0 = fmaxf(fmaf(bf_lo(v), ss[c],     ss[128 + c]),     0.f);
    float a1 = fmaxf(fmaf(bf_hi(v), ss[c + 1], ss[128 + c + 1]), 0.f);
    float p = a0 * Wl[c] + a1 * Wl[c + 1];
    #pragma unroll
    for (int o = 32; o; o >>= 1) p += __shfl_xor(p, o);
    if (lane == 0) {
        float z = fmaxf(p + bl[0], 0.f);
        out[node] = 1.f / (1.f + expf(-z));
    }
}

extern "C" void kernel_launch(void* const* d_in, const int* in_sizes, int n_in,
                              void* d_out, int out_size, void* d_ws, size_t ws_size,
                              hipStream_t stream) {
    const float* x   = (const float*)d_in[0];
    const int*   ei  = (const int*)d_in[1];
    const float* W1  = (const float*)d_in[2];
    const float* b1  = (const float*)d_in[3];
    const float* g1  = (const float*)d_in[4];
    const float* be1 = (const float*)d_in[5];
    const float* W2  = (const float*)d_in[6];
    const float* b2  = (const float*)d_in[7];
    const float* g2  = (const float*)d_in[8];
    const float* be2 = (const float*)d_in[9];
    const float* Wl  = (const float*)d_in[10];
    const float* bl  = (const float*)d_in[11];

    const int N = in_sizes[0] / 128;
    const int E = in_sizes[1] / 2;
    const int* src  = ei;
    const int* dstp = ei + E;

    const int NBKT  = (N + 255) >> 8;          // coarse buckets (391)
    const int n2    = NBKT * 256;              // cnt2d size
    const int NB2   = (n2 + 1023) / 1024;      // scan blocks
    const int CHUNK = (E + 255) / 256;         // edges per histogram block

    char* ws = (char*)d_ws;
    size_t off = 0;
    auto alloc = [&](size_t bytes) {
        void* p = ws + off;
        off += (bytes + 255) & ~(size_t)255;
        return p;
    };
    int*    cnt    = (int*)   alloc((size_t)N * 4);
    float*  dinv   = (float*) alloc((size_t)N * 4);
    int*    offs   = (int*)   alloc((size_t)(N + 1) * 4);
    int*    cnt2d  = (int*)   alloc((size_t)n2 * 4);
    int*    cnt2dx = (int*)   alloc((size_t)n2 * 4);
    int*    bsum   = (int*)   alloc(1024 * 4);
    uint*   ebuf   = (uint*)  alloc((size_t)E * 4);
    int*    csr    = (int*)   alloc((size_t)E * 4);
    float*  sums   = (float*) alloc(512 * 4);
    float*  ss     = (float*) alloc(512 * 4);
    ushort* WT1    = (ushort*)alloc(128 * 128 * 2);
    ushort* WT2    = (ushort*)alloc(128 * 128 * 2);
    ushort* hbuf   = (ushort*)alloc((size_t)N * 128 * 2);
    ushort* abuf   = (ushort*)alloc((size_t)N * 128 * 2);

    hipMemsetAsync(sums, 0, 512 * 4, stream);

    // ---- CSR build (bucketed counting sort) ----
    k_bcount   <<<256, 256, 0, stream>>>(dstp, E, CHUNK, cnt2d, NBKT);
    k_scan_local<<<NB2, 256, 0, stream>>>(cnt2d, n2, cnt2dx, bsum);
    k_scan_bsum <<<1, 1024, 0, stream>>>(bsum, NB2, offs + N);
    k_scan_add  <<<NB2, 256, 0, stream>>>(cnt2dx, n2, bsum);
    k_bscatter <<<256, 256, 0, stream>>>(src, dstp, E, CHUNK, cnt2dx, ebuf, NBKT);
    k_bcsr     <<<NBKT, 256, 0, stream>>>(ebuf, cnt2dx, E, N, NBKT, cnt, offs, csr);
    k_dinv     <<<(N + 255) / 256, 256, 0, stream>>>(cnt, dinv, N);

    // ---- weight prep ----
    k_wprep<<<64, 256, 0, stream>>>(W1, WT1);
    k_wprep<<<64, 256, 0, stream>>>(W2, WT2);

    // ---- layer 1 ----
    k_gemm<0> <<<(N + 63) / 64, 256, 0, stream>>>(x, WT1, nullptr, dinv, hbuf, N);
    k_gather  <<<(N + 3) / 4, 256, 0, stream>>>((const uint*)hbuf, offs, csr, dinv, b1, (uint*)abuf, N);
    k_stats   <<<512, 256, 0, stream>>>((const uint*)abuf, N, sums);
    k_bnparam <<<1, 128, 0, stream>>>(sums, g1, be1, N, ss);

    // ---- layer 2 (BN1+ReLU fused into GEMM2's A-frag load) ----
    k_gemm<1> <<<(N + 63) / 64, 256, 0, stream>>>(abuf, WT2, ss, dinv, hbuf, N);
    k_gather  <<<(N + 3) / 4, 256, 0, stream>>>((const uint*)hbuf, offs, csr, dinv, b2, (uint*)abuf, N);
    k_stats   <<<512, 256, 0, stream>>>((const uint*)abuf, N, sums + 256);
    k_bnparam <<<1, 128, 0, stream>>>(sums + 256, g2, be2, N, ss + 256);

    // ---- head (BN2+ReLU fused) ----
    k_final<<<(N + 3) / 4, 256, 0, stream>>>((const uint*)abuf, ss + 256, Wl, bl, (float*)d_out, N);
}

// Round 6
// 367.449 us; speedup vs baseline: 2.3661x; 1.0163x over previous
//
#include <hip/hip_runtime.h>
#include <cstdint>
#include <cstddef>

typedef unsigned int uint;
typedef unsigned short ushort;
typedef __attribute__((ext_vector_type(8))) short bf16x8;
typedef __attribute__((ext_vector_type(4))) float f32x4;

__device__ __forceinline__ ushort f2bf(float f) {          // RNE float->bf16
    uint b = __float_as_uint(f);
    return (ushort)((b + 0x7FFF + ((b >> 16) & 1)) >> 16);
}
__device__ __forceinline__ float bf_lo(uint u) { return __uint_as_float(u << 16); }
__device__ __forceinline__ float bf_hi(uint u) { return __uint_as_float(u & 0xFFFF0000u); }

// ============ CSR build via bucketed counting sort (no global atomics) ======
// bucket b = dst >> 8. NBKT <= 512, CHUNK <= 8192 assumed (N<=128K, E<=2.09M).

// P1: per-block coarse histogram -> cnt2d[b*256 + blk]
__global__ __launch_bounds__(256) void k_bcount(
        const int* __restrict__ dst, int E, int chunk,
        int* __restrict__ cnt2d, int nbkt) {
    __shared__ int hist[512];
    for (int b = threadIdx.x; b < nbkt; b += 256) hist[b] = 0;
    __syncthreads();
    const int beg = blockIdx.x * chunk;
    const int end = min(beg + chunk, E);
    for (int i = beg + threadIdx.x; i < end; i += 256)
        atomicAdd(&hist[dst[i] >> 8], 1);
    __syncthreads();
    for (int b = threadIdx.x; b < nbkt; b += 256)
        cnt2d[b * 256 + blockIdx.x] = hist[b];
}

// P2: LDS-staged scatter — locally bucket-sort the chunk, then write each
// (bucket,block) slice as a contiguous run (kills write amplification).
__global__ __launch_bounds__(256) void k_bscatter(
        const int* __restrict__ src, const int* __restrict__ dst, int E, int chunk,
        const int* __restrict__ cnt2d, const int* __restrict__ cnt2dx,
        uint* __restrict__ ebuf, int nbkt) {
    __shared__ uint   ebuf_l[8192];
    __shared__ ushort bid_l[8192];
    __shared__ int    sh[256];
    __shared__ int    histx[512];
    __shared__ int    cur[512];
    __shared__ int    goff[512];
    const int t   = threadIdx.x;
    const int blk = blockIdx.x;

    // local counts for this block, exclusive-scan over buckets (2 per thread)
    const int b0 = 2 * t, b1 = 2 * t + 1;
    const int c0 = (b0 < nbkt) ? cnt2d[b0 * 256 + blk] : 0;
    const int c1 = (b1 < nbkt) ? cnt2d[b1 * 256 + blk] : 0;
    sh[t] = c0 + c1;
    __syncthreads();
    #pragma unroll
    for (int o = 1; o < 256; o <<= 1) {
        int x = (t >= o) ? sh[t - o] : 0;
        __syncthreads();
        sh[t] += x;
        __syncthreads();
    }
    const int ex = sh[t] - (c0 + c1);
    histx[b0] = ex;       histx[b1] = ex + c0;
    cur[b0]   = ex;       cur[b1]   = ex + c0;
    goff[b0] = ((b0 < nbkt) ? cnt2dx[b0 * 256 + blk] : 0) - histx[b0];
    goff[b1] = ((b1 < nbkt) ? cnt2dx[b1 * 256 + blk] : 0) - histx[b1];
    __syncthreads();

    // place edges into LDS, bucket-sorted
    const int beg = blk * chunk;
    const int end = min(beg + chunk, E);
    for (int i = beg + t; i < end; i += 256) {
        int d = dst[i];
        int s = src[i];
        int b = d >> 8;
        int p = atomicAdd(&cur[b], 1);            // LDS atomic
        ebuf_l[p] = ((uint)(d & 255) << 17) | (uint)s;
        bid_l[p]  = (ushort)b;
    }
    __syncthreads();

    // write out: consecutive i within a bucket -> consecutive global slots
    const int cntE = end - beg;
    for (int i = t; i < cntE; i += 256)
        ebuf[goff[bid_l[i]] + i] = ebuf_l[i];
}

// P3: one block per bucket: fine counts -> dinv, offs, grouped csr
__global__ __launch_bounds__(256) void k_bcsr(
        const uint* __restrict__ ebuf, const int* __restrict__ cnt2dx,
        int E, int n, int nbkt,
        float* __restrict__ dinv, int* __restrict__ offs, int* __restrict__ csr) {
    __shared__ int fine[256], finex[256], fcur[256];
    const int b = blockIdx.x;
    const int t = threadIdx.x;
    const int ebeg = cnt2dx[b * 256];
    const int eend = (b + 1 < nbkt) ? cnt2dx[(b + 1) * 256] : E;
    fine[t] = 0;
    __syncthreads();
    for (int i = ebeg + t; i < eend; i += 256)
        atomicAdd(&fine[ebuf[i] >> 17], 1);
    __syncthreads();
    const int node = b * 256 + t;
    if (node < n) dinv[node] = rsqrtf((float)(fine[t] + 1));   // fused k_dinv
    int v = fine[t];
    finex[t] = v;
    __syncthreads();
    #pragma unroll
    for (int o = 1; o < 256; o <<= 1) {
        int x = (t >= o) ? finex[t - o] : 0;
        __syncthreads();
        finex[t] += x;
        __syncthreads();
    }
    const int ex = finex[t] - v;
    fcur[t] = ex;
    if (node <= n) offs[node] = ebeg + ex;
    if (b == 0 && t == 0) offs[n] = E;
    __syncthreads();
    for (int i = ebeg + t; i < eend; i += 256) {
        uint e = ebuf[i];
        int f = (int)(e >> 17);
        int p = atomicAdd(&fcur[f], 1);             // LDS atomic
        csr[ebeg + p] = (int)(e & 0x1FFFF);
    }
}

// ---------------- hierarchical exclusive scan (used on cnt2d) --------------
__global__ __launch_bounds__(256) void k_scan_local(
        const int* __restrict__ cnt, int n,
        int* __restrict__ offs, int* __restrict__ bsum) {
    __shared__ int sh[256];
    const int base = blockIdx.x * 1024 + threadIdx.x * 4;
    int v[4];
    #pragma unroll
    for (int j = 0; j < 4; j++) { int g = base + j; v[j] = (g < n) ? cnt[g] : 0; }
    const int tsum = v[0] + v[1] + v[2] + v[3];
    sh[threadIdx.x] = tsum;
    __syncthreads();
    #pragma unroll
    for (int o = 1; o < 256; o <<= 1) {
        int t = (threadIdx.x >= (unsigned)o) ? sh[threadIdx.x - o] : 0;
        __syncthreads();
        sh[threadIdx.x] += t;
        __syncthreads();
    }
    int run = sh[threadIdx.x] - tsum;
    #pragma unroll
    for (int j = 0; j < 4; j++) {
        int g = base + j;
        if (g < n) offs[g] = run;
        run += v[j];
    }
    if (threadIdx.x == 255) bsum[blockIdx.x] = sh[255];
}

__global__ __launch_bounds__(1024) void k_scan_bsum(
        int* __restrict__ bsum, int nb, int* __restrict__ total) {
    __shared__ int sh[1024];
    const int t = threadIdx.x;
    int v = (t < nb) ? bsum[t] : 0;
    sh[t] = v;
    __syncthreads();
    #pragma unroll
    for (int o = 1; o < 1024; o <<= 1) {
        int x = (t >= (unsigned)o) ? sh[t - o] : 0;
        __syncthreads();
        sh[t] += x;
        __syncthreads();
    }
    if (t < nb) bsum[t] = sh[t] - v;
    if (t == 1023) *total = sh[1023];
}

__global__ __launch_bounds__(256) void k_scan_add(
        int* __restrict__ offs, int n, const int* __restrict__ bsum) {
    const int add = bsum[blockIdx.x];
    const int base = blockIdx.x * 1024;
    #pragma unroll
    for (int j = 0; j < 4; j++) {
        int g = base + threadIdx.x + j * 256;
        if (g < n) offs[g] += add;
    }
}

// ------------- W1+W2 transpose + bf16 convert, and zero the sums -----------
__global__ void k_wprep(const float* __restrict__ W1, const float* __restrict__ W2,
                        ushort* __restrict__ WT1, ushort* __restrict__ WT2,
                        float* __restrict__ sums) {
    int idx = blockIdx.x * 256 + threadIdx.x;   // 32768 total
    if (idx < 512) sums[idx] = 0.f;
    int n = (idx >> 7) & 127, k = idx & 127;
    if (idx < 16384) WT1[idx] = f2bf(W1[k * 128 + n]);
    else             WT2[idx - 16384] = f2bf(W2[k * 128 + n]);
}

// ---------------- MFMA GEMM: C[n,128](bf16) = dinv[r] * f(A) @ W -------------
// LAYER 0: A fp32, f = identity. LAYER 1: A bf16, f = relu(BN(a)) with BN
// scale/shift derived in-block from sums/g/be (fused k_bnparam).
template <int LAYER>
__global__ __launch_bounds__(256) void k_gemm(
        const void* __restrict__ Av, const ushort* __restrict__ WT,
        const float* __restrict__ sums, const float* __restrict__ g,
        const float* __restrict__ be, const float* __restrict__ dinv,
        ushort* __restrict__ C, int n, float invn) {
    __shared__ float ssl[256];
    const int tid = threadIdx.x;
    if (LAYER == 1) {
        if (tid < 128) {
            float mean = sums[tid] * invn;
            float var  = sums[128 + tid] * invn - mean * mean;
            float inv  = rsqrtf(var + 1e-5f);
            float sc   = g[tid] * inv;
            ssl[tid]       = sc;
            ssl[128 + tid] = be[tid] - mean * sc;
        }
        __syncthreads();
    }

    const int lane = tid & 63;
    const int wid  = tid >> 6;
    const int m0   = blockIdx.x * 64 + wid * 16;
    const int lm   = lane & 15;
    const int lq   = lane >> 4;
    const int row  = m0 + lm;
    const bool rv  = row < n;

    f32x4 acc[8];
    #pragma unroll
    for (int i = 0; i < 8; i++) acc[i] = (f32x4){0.f, 0.f, 0.f, 0.f};

    #pragma unroll
    for (int ks = 0; ks < 4; ks++) {
        const int kb = ks * 32 + lq * 8;
        bf16x8 af;
        if (LAYER == 0) {
            const float* A = (const float*)Av;
            float4 v0, v1;
            if (rv) {
                v0 = *(const float4*)&A[(size_t)row * 128 + kb];
                v1 = *(const float4*)&A[(size_t)row * 128 + kb + 4];
            } else {
                v0 = make_float4(0.f, 0.f, 0.f, 0.f);
                v1 = v0;
            }
            af[0] = (short)f2bf(v0.x); af[1] = (short)f2bf(v0.y);
            af[2] = (short)f2bf(v0.z); af[3] = (short)f2bf(v0.w);
            af[4] = (short)f2bf(v1.x); af[5] = (short)f2bf(v1.y);
            af[6] = (short)f2bf(v1.z); af[7] = (short)f2bf(v1.w);
        } else {
            const uint* A = (const uint*)Av;
            uint4 u = rv ? *(const uint4*)&A[(size_t)row * 64 + kb / 2]
                         : make_uint4(0, 0, 0, 0);
            float4 sc0 = *(const float4*)&ssl[kb];
            float4 sc1 = *(const float4*)&ssl[kb + 4];
            float4 sh0 = *(const float4*)&ssl[128 + kb];
            float4 sh1 = *(const float4*)&ssl[128 + kb + 4];
            float f0 = fmaxf(fmaf(bf_lo(u.x), sc0.x, sh0.x), 0.f);
            float f1 = fmaxf(fmaf(bf_hi(u.x), sc0.y, sh0.y), 0.f);
            float f2 = fmaxf(fmaf(bf_lo(u.y), sc0.z, sh0.z), 0.f);
            float f3 = fmaxf(fmaf(bf_hi(u.y), sc0.w, sh0.w), 0.f);
            float f4 = fmaxf(fmaf(bf_lo(u.z), sc1.x, sh1.x), 0.f);
            float f5 = fmaxf(fmaf(bf_hi(u.z), sc1.y, sh1.y), 0.f);
            float f6 = fmaxf(fmaf(bf_lo(u.w), sc1.z, sh1.z), 0.f);
            float f7 = fmaxf(fmaf(bf_hi(u.w), sc1.w, sh1.w), 0.f);
            af[0] = (short)f2bf(f0); af[1] = (short)f2bf(f1);
            af[2] = (short)f2bf(f2); af[3] = (short)f2bf(f3);
            af[4] = (short)f2bf(f4); af[5] = (short)f2bf(f5);
            af[6] = (short)f2bf(f6); af[7] = (short)f2bf(f7);
        }
        #pragma unroll
        for (int nt = 0; nt < 8; nt++) {
            bf16x8 bfr = *(const bf16x8*)&WT[(size_t)(nt * 16 + lm) * 128 + kb];
            acc[nt] = __builtin_amdgcn_mfma_f32_16x16x32_bf16(af, bfr, acc[nt], 0, 0, 0);
        }
    }

    const int orow0 = m0 + lq * 4;
    #pragma unroll
    for (int r = 0; r < 4; r++) {
        const int orow = orow0 + r;
        if (orow < n) {
            const float s = dinv[orow];
            #pragma unroll
            for (int nt = 0; nt < 8; nt++)
                C[(size_t)orow * 128 + nt * 16 + lm] = f2bf(acc[nt][r] * s);
        }
    }
}

// ---------------- gather-aggregate (one wave per node, bf16 rows) -----------
__global__ __launch_bounds__(256) void k_gather(
        const uint* __restrict__ hs, const int* __restrict__ offs,
        const int* __restrict__ csr, const float* __restrict__ dinv,
        const float* __restrict__ bias, uint* __restrict__ out, int n) {
    int node = (blockIdx.x * blockDim.x + threadIdx.x) >> 6;
    int lane = threadIdx.x & 63;
    if (node >= n) return;
    const float di = dinv[node];
    const int beg = offs[node], end = offs[node + 1];
    const int c = lane * 2;

    uint hv = hs[(size_t)node * 64 + lane];
    float ax = bf_lo(hv), ay = bf_hi(hv);       // self loop (prescaled)

    int e = beg;
    if (e + 8 <= end) {
        int idx[8];
        #pragma unroll
        for (int j = 0; j < 8; j++) idx[j] = csr[e + j];
        while (e + 16 <= end) {
            uint v[8];
            #pragma unroll
            for (int j = 0; j < 8; j++) v[j] = hs[(size_t)idx[j] * 64 + lane];
            #pragma unroll
            for (int j = 0; j < 8; j++) idx[j] = csr[e + 8 + j];
            #pragma unroll
            for (int j = 0; j < 8; j++) { ax += bf_lo(v[j]); ay += bf_hi(v[j]); }
            e += 8;
        }
        uint v[8];
        #pragma unroll
        for (int j = 0; j < 8; j++) v[j] = hs[(size_t)idx[j] * 64 + lane];
        #pragma unroll
        for (int j = 0; j < 8; j++) { ax += bf_lo(v[j]); ay += bf_hi(v[j]); }
        e += 8;
    }
    for (; e < end; ++e) {
        uint v = hs[(size_t)csr[e] * 64 + lane];
        ax += bf_lo(v); ay += bf_hi(v);
    }
    float ox = fmaf(di, ax, bias[c]);
    float oy = fmaf(di, ay, bias[c + 1]);
    out[(size_t)node * 64 + lane] = (uint)f2bf(ox) | ((uint)f2bf(oy) << 16);
}

// ---------------- BN stats (packed uint loads) ----------------
__global__ __launch_bounds__(256) void k_stats(
        const uint* __restrict__ h, int n, float* __restrict__ sums) {
    const int j   = threadIdx.x & 63;
    const int sub = threadIdx.x >> 6;
    float slo = 0.f, s2lo = 0.f, shi = 0.f, s2hi = 0.f;
    for (int r = blockIdx.x * 4 + sub; r < n; r += gridDim.x * 4) {
        uint u = h[(size_t)r * 64 + j];
        float a = bf_lo(u), b = bf_hi(u);
        slo += a; s2lo = fmaf(a, a, s2lo);
        shi += b; s2hi = fmaf(b, b, s2hi);
    }
    __shared__ float sh[4][256];
    sh[0][threadIdx.x] = slo; sh[1][threadIdx.x] = s2lo;
    sh[2][threadIdx.x] = shi; sh[3][threadIdx.x] = s2hi;
    __syncthreads();
    if (sub == 0) {
        float a0 = 0.f, a1 = 0.f, a2 = 0.f, a3 = 0.f;
        #pragma unroll
        for (int t = 0; t < 4; t++) {
            a0 += sh[0][t * 64 + j]; a1 += sh[1][t * 64 + j];
            a2 += sh[2][t * 64 + j]; a3 += sh[3][t * 64 + j];
        }
        atomicAdd(&sums[2 * j],           a0);
        atomicAdd(&sums[128 + 2 * j],     a1);
        atomicAdd(&sums[2 * j + 1],       a2);
        atomicAdd(&sums[128 + 2 * j + 1], a3);
    }
}

// ---------------- head (BN2 derived in-block, fused k_bnparam) --------------
__global__ __launch_bounds__(1024) void k_final(
        const uint* __restrict__ h, const float* __restrict__ sums,
        const float* __restrict__ g, const float* __restrict__ be,
        const float* __restrict__ Wl, const float* __restrict__ bl,
        float* __restrict__ out, int n, float invn) {
    __shared__ float ssl[256];
    const int t = threadIdx.x;
    if (t < 128) {
        float mean = sums[t] * invn;
        float var  = sums[128 + t] * invn - mean * mean;
        float inv  = rsqrtf(var + 1e-5f);
        float sc   = g[t] * inv;
        ssl[t]       = sc;
        ssl[128 + t] = be[t] - mean * sc;
    }
    __syncthreads();
    int node = (blockIdx.x * 1024 + t) >> 6;
    int lane = t & 63;
    if (node >= n) return;
    int c = lane * 2;
    uint v = h[(size_t)node * 64 + lane];
    float a0 = fmaxf(fmaf(bf_lo(v), ssl[c],     ssl[128 + c]),     0.f);
    float a1 = fmaxf(fmaf(bf_hi(v), ssl[c + 1], ssl[128 + c + 1]), 0.f);
    float p = a0 * Wl[c] + a1 * Wl[c + 1];
    #pragma unroll
    for (int o = 32; o; o >>= 1) p += __shfl_xor(p, o);
    if (lane == 0) {
        float z = fmaxf(p + bl[0], 0.f);
        out[node] = 1.f / (1.f + expf(-z));
    }
}

extern "C" void kernel_launch(void* const* d_in, const int* in_sizes, int n_in,
                              void* d_out, int out_size, void* d_ws, size_t ws_size,
                              hipStream_t stream) {
    const float* x   = (const float*)d_in[0];
    const int*   ei  = (const int*)d_in[1];
    const float* W1  = (const float*)d_in[2];
    const float* b1  = (const float*)d_in[3];
    const float* g1  = (const float*)d_in[4];
    const float* be1 = (const float*)d_in[5];
    const float* W2  = (const float*)d_in[6];
    const float* b2  = (const float*)d_in[7];
    const float* g2  = (const float*)d_in[8];
    const float* be2 = (const float*)d_in[9];
    const float* Wl  = (const float*)d_in[10];
    const float* bl  = (const float*)d_in[11];

    const int N = in_sizes[0] / 128;
    const int E = in_sizes[1] / 2;
    const int* src  = ei;
    const int* dstp = ei + E;

    const int NBKT  = (N + 255) >> 8;          // coarse buckets
    const int n2    = NBKT * 256;              // cnt2d size
    const int NB2   = (n2 + 1023) / 1024;      // scan blocks
    const int CHUNK = (E + 255) / 256;         // edges per block (<= 8192)

    char* ws = (char*)d_ws;
    size_t off = 0;
    auto alloc = [&](size_t bytes) {
        void* p = ws + off;
        off += (bytes + 255) & ~(size_t)255;
        return p;
    };
    float*  dinv   = (float*) alloc((size_t)N * 4);
    int*    offs   = (int*)   alloc((size_t)(N + 1) * 4);
    int*    cnt2d  = (int*)   alloc((size_t)n2 * 4);
    int*    cnt2dx = (int*)   alloc((size_t)n2 * 4);
    int*    bsum   = (int*)   alloc(1024 * 4);
    uint*   ebuf   = (uint*)  alloc((size_t)E * 4);
    int*    csr    = (int*)   alloc((size_t)E * 4);
    float*  sums   = (float*) alloc(512 * 4);
    ushort* WT1    = (ushort*)alloc(128 * 128 * 2);
    ushort* WT2    = (ushort*)alloc(128 * 128 * 2);
    ushort* hbuf   = (ushort*)alloc((size_t)N * 128 * 2);
    ushort* abuf   = (ushort*)alloc((size_t)N * 128 * 2);

    const float invn = 1.f / (float)N;

    // weight prep + sums zeroing (independent of graph)
    k_wprep<<<128, 256, 0, stream>>>(W1, W2, WT1, WT2, sums);

    // ---- CSR build (bucketed counting sort, LDS-staged writes) ----
    k_bcount    <<<256, 256, 0, stream>>>(dstp, E, CHUNK, cnt2d, NBKT);
    k_scan_local<<<NB2, 256, 0, stream>>>(cnt2d, n2, cnt2dx, bsum);
    k_scan_bsum <<<1, 1024, 0, stream>>>(bsum, NB2, offs + N);
    k_scan_add  <<<NB2, 256, 0, stream>>>(cnt2dx, n2, bsum);
    k_bscatter  <<<256, 256, 0, stream>>>(src, dstp, E, CHUNK, cnt2d, cnt2dx, ebuf, NBKT);
    k_bcsr      <<<NBKT, 256, 0, stream>>>(ebuf, cnt2dx, E, N, NBKT, dinv, offs, csr);

    // ---- layer 1 ----
    k_gemm<0> <<<(N + 63) / 64, 256, 0, stream>>>(x, WT1, nullptr, nullptr, nullptr, dinv, hbuf, N, invn);
    k_gather  <<<(N + 3) / 4, 256, 0, stream>>>((const uint*)hbuf, offs, csr, dinv, b1, (uint*)abuf, N);
    k_stats   <<<512, 256, 0, stream>>>((const uint*)abuf, N, sums);

    // ---- layer 2 (BN1+ReLU and BN-param derivation fused into GEMM2) ----
    k_gemm<1> <<<(N + 63) / 64, 256, 0, stream>>>(abuf, WT2, sums, g1, be1, dinv, hbuf, N, invn);
    k_gather  <<<(N + 3) / 4, 256, 0, stream>>>((const uint*)hbuf, offs, csr, dinv, b2, (uint*)abuf, N);
    k_stats   <<<512, 256, 0, stream>>>((const uint*)abuf, N, sums + 256);

    // ---- head (BN2 derived in-block) ----
    k_final<<<(N + 15) / 16, 1024, 0, stream>>>((const uint*)abuf, sums + 256, g2, be2, Wl, bl, (float*)d_out, N, invn);
}

// Round 7
// 359.049 us; speedup vs baseline: 2.4215x; 1.0234x over previous
//
#include <hip/hip_runtime.h>
#include <cstdint>
#include <cstddef>

typedef unsigned int uint;
typedef unsigned short ushort;
typedef __attribute__((ext_vector_type(8))) short bf16x8;
typedef __attribute__((ext_vector_type(4))) float f32x4;

__device__ __forceinline__ ushort f2bf(float f) {          // RNE float->bf16
    uint b = __float_as_uint(f);
    return (ushort)((b + 0x7FFF + ((b >> 16) & 1)) >> 16);
}
__device__ __forceinline__ float bf_lo(uint u) { return __uint_as_float(u << 16); }
__device__ __forceinline__ float bf_hi(uint u) { return __uint_as_float(u & 0xFFFF0000u); }

// ============ CSR build via bucketed counting sort (no global atomics) ======
// bucket b = dst >> 8. NBKT <= 512, CHUNK <= 8192 assumed.

// P1: per-block coarse histogram -> cnt2d[b*256 + blk]; blocks >=256 do W-prep.
__global__ __launch_bounds__(256) void k_bcount(
        const int* __restrict__ dst, int E, int chunk,
        int* __restrict__ cnt2d, int nbkt,
        const float* __restrict__ W1, const float* __restrict__ W2,
        ushort* __restrict__ WT1, ushort* __restrict__ WT2,
        float* __restrict__ sums) {
    __shared__ int hist[512];
    if (blockIdx.x >= 256) {                    // fused weight prep + sums zero
        int idx = (blockIdx.x - 256) * 256 + threadIdx.x;   // 0..32767
        if (idx < 512) sums[idx] = 0.f;
        int nn = (idx >> 7) & 127, k = idx & 127;
        if (idx < 16384) WT1[idx] = f2bf(W1[k * 128 + nn]);
        else             WT2[idx - 16384] = f2bf(W2[k * 128 + nn]);
        return;
    }
    for (int b = threadIdx.x; b < nbkt; b += 256) hist[b] = 0;
    __syncthreads();
    const int beg = blockIdx.x * chunk;
    const int end = min(beg + chunk, E);
    for (int i = beg + threadIdx.x; i < end; i += 256)
        atomicAdd(&hist[dst[i] >> 8], 1);
    __syncthreads();
    for (int b = threadIdx.x; b < nbkt; b += 256)
        cnt2d[b * 256 + blockIdx.x] = hist[b];
}

// P2: LDS-staged scatter — locally bucket-sort the chunk, then write each
// (bucket,block) slice as a contiguous run.
__global__ __launch_bounds__(256) void k_bscatter(
        const int* __restrict__ src, const int* __restrict__ dst, int E, int chunk,
        const int* __restrict__ cnt2d, const int* __restrict__ cnt2dx,
        uint* __restrict__ ebuf, int nbkt) {
    __shared__ uint   ebuf_l[8192];
    __shared__ ushort bid_l[8192];
    __shared__ int    sh[256];
    __shared__ int    histx[512];
    __shared__ int    cur[512];
    __shared__ int    goff[512];
    const int t   = threadIdx.x;
    const int blk = blockIdx.x;

    const int b0 = 2 * t, b1 = 2 * t + 1;
    const int c0 = (b0 < nbkt) ? cnt2d[b0 * 256 + blk] : 0;
    const int c1 = (b1 < nbkt) ? cnt2d[b1 * 256 + blk] : 0;
    sh[t] = c0 + c1;
    __syncthreads();
    #pragma unroll
    for (int o = 1; o < 256; o <<= 1) {
        int x = (t >= o) ? sh[t - o] : 0;
        __syncthreads();
        sh[t] += x;
        __syncthreads();
    }
    const int ex = sh[t] - (c0 + c1);
    histx[b0] = ex;       histx[b1] = ex + c0;
    cur[b0]   = ex;       cur[b1]   = ex + c0;
    goff[b0] = ((b0 < nbkt) ? cnt2dx[b0 * 256 + blk] : 0) - histx[b0];
    goff[b1] = ((b1 < nbkt) ? cnt2dx[b1 * 256 + blk] : 0) - histx[b1];
    __syncthreads();

    const int beg = blk * chunk;
    const int end = min(beg + chunk, E);
    for (int i = beg + t; i < end; i += 256) {
        int d = dst[i];
        int s = src[i];
        int b = d >> 8;
        int p = atomicAdd(&cur[b], 1);            // LDS atomic
        ebuf_l[p] = ((uint)(d & 255) << 17) | (uint)s;
        bid_l[p]  = (ushort)b;
    }
    __syncthreads();

    const int cntE = end - beg;
    for (int i = t; i < cntE; i += 256)
        ebuf[goff[bid_l[i]] + i] = ebuf_l[i];
}

// P3: one block per bucket: fine counts -> dinv, offs, grouped csr
__global__ __launch_bounds__(256) void k_bcsr(
        const uint* __restrict__ ebuf, const int* __restrict__ cnt2dx,
        int E, int n, int nbkt,
        float* __restrict__ dinv, int* __restrict__ offs, int* __restrict__ csr) {
    __shared__ int fine[256], finex[256], fcur[256];
    const int b = blockIdx.x;
    const int t = threadIdx.x;
    const int ebeg = cnt2dx[b * 256];
    const int eend = (b + 1 < nbkt) ? cnt2dx[(b + 1) * 256] : E;
    fine[t] = 0;
    __syncthreads();
    for (int i = ebeg + t; i < eend; i += 256)
        atomicAdd(&fine[ebuf[i] >> 17], 1);
    __syncthreads();
    const int node = b * 256 + t;
    if (node < n) dinv[node] = rsqrtf((float)(fine[t] + 1));
    int v = fine[t];
    finex[t] = v;
    __syncthreads();
    #pragma unroll
    for (int o = 1; o < 256; o <<= 1) {
        int x = (t >= o) ? finex[t - o] : 0;
        __syncthreads();
        finex[t] += x;
        __syncthreads();
    }
    const int ex = finex[t] - v;
    fcur[t] = ex;
    if (node <= n) offs[node] = ebeg + ex;
    if (b == 0 && t == 0) offs[n] = E;
    __syncthreads();
    for (int i = ebeg + t; i < eend; i += 256) {
        uint e = ebuf[i];
        int f = (int)(e >> 17);
        int p = atomicAdd(&fcur[f], 1);             // LDS atomic
        csr[ebeg + p] = (int)(e & 0x1FFFF);
    }
}

// ---------------- hierarchical exclusive scan (used on cnt2d) --------------
__global__ __launch_bounds__(256) void k_scan_local(
        const int* __restrict__ cnt, int n,
        int* __restrict__ offs, int* __restrict__ bsum) {
    __shared__ int sh[256];
    const int base = blockIdx.x * 1024 + threadIdx.x * 4;
    int v[4];
    #pragma unroll
    for (int j = 0; j < 4; j++) { int g = base + j; v[j] = (g < n) ? cnt[g] : 0; }
    const int tsum = v[0] + v[1] + v[2] + v[3];
    sh[threadIdx.x] = tsum;
    __syncthreads();
    #pragma unroll
    for (int o = 1; o < 256; o <<= 1) {
        int t = (threadIdx.x >= (unsigned)o) ? sh[threadIdx.x - o] : 0;
        __syncthreads();
        sh[threadIdx.x] += t;
        __syncthreads();
    }
    int run = sh[threadIdx.x] - tsum;
    #pragma unroll
    for (int j = 0; j < 4; j++) {
        int g = base + j;
        if (g < n) offs[g] = run;
        run += v[j];
    }
    if (threadIdx.x == 255) bsum[blockIdx.x] = sh[255];
}

// add-back; each block derives its own prefix from bsum (nb <= 256)
__global__ __launch_bounds__(256) void k_scan_add(
        int* __restrict__ offs, int n, const int* __restrict__ bsum, int nb) {
    __shared__ int red[256];
    const int t = threadIdx.x;
    red[t] = (t < nb && t < (int)blockIdx.x) ? bsum[t] : 0;
    __syncthreads();
    #pragma unroll
    for (int o = 128; o; o >>= 1) {
        if (t < o) red[t] += red[t + o];
        __syncthreads();
    }
    const int add = red[0];
    const int base = blockIdx.x * 1024;
    #pragma unroll
    for (int j = 0; j < 4; j++) {
        int g = base + t + j * 256;
        if (g < n) offs[g] += add;
    }
}

// ---------------- MFMA GEMM: C[n,128](bf16) = dinv[r] * f(A) @ W -------------
template <int LAYER>
__global__ __launch_bounds__(256) void k_gemm(
        const void* __restrict__ Av, const ushort* __restrict__ WT,
        const float* __restrict__ sums, const float* __restrict__ g,
        const float* __restrict__ be, const float* __restrict__ dinv,
        ushort* __restrict__ C, int n, float invn) {
    __shared__ float ssl[256];
    const int tid = threadIdx.x;
    if (LAYER == 1) {
        if (tid < 128) {
            float mean = sums[tid] * invn;
            float var  = sums[128 + tid] * invn - mean * mean;
            float inv  = rsqrtf(var + 1e-5f);
            float sc   = g[tid] * inv;
            ssl[tid]       = sc;
            ssl[128 + tid] = be[tid] - mean * sc;
        }
        __syncthreads();
    }

    const int lane = tid & 63;
    const int wid  = tid >> 6;
    const int m0   = blockIdx.x * 64 + wid * 16;
    const int lm   = lane & 15;
    const int lq   = lane >> 4;
    const int row  = m0 + lm;
    const bool rv  = row < n;

    f32x4 acc[8];
    #pragma unroll
    for (int i = 0; i < 8; i++) acc[i] = (f32x4){0.f, 0.f, 0.f, 0.f};

    #pragma unroll
    for (int ks = 0; ks < 4; ks++) {
        const int kb = ks * 32 + lq * 8;
        bf16x8 af;
        if (LAYER == 0) {
            const float* A = (const float*)Av;
            float4 v0, v1;
            if (rv) {
                v0 = *(const float4*)&A[(size_t)row * 128 + kb];
                v1 = *(const float4*)&A[(size_t)row * 128 + kb + 4];
            } else {
                v0 = make_float4(0.f, 0.f, 0.f, 0.f);
                v1 = v0;
            }
            af[0] = (short)f2bf(v0.x); af[1] = (short)f2bf(v0.y);
            af[2] = (short)f2bf(v0.z); af[3] = (short)f2bf(v0.w);
            af[4] = (short)f2bf(v1.x); af[5] = (short)f2bf(v1.y);
            af[6] = (short)f2bf(v1.z); af[7] = (short)f2bf(v1.w);
        } else {
            const uint* A = (const uint*)Av;
            uint4 u = rv ? *(const uint4*)&A[(size_t)row * 64 + kb / 2]
                         : make_uint4(0, 0, 0, 0);
            float4 sc0 = *(const float4*)&ssl[kb];
            float4 sc1 = *(const float4*)&ssl[kb + 4];
            float4 sh0 = *(const float4*)&ssl[128 + kb];
            float4 sh1 = *(const float4*)&ssl[128 + kb + 4];
            float f0 = fmaxf(fmaf(bf_lo(u.x), sc0.x, sh0.x), 0.f);
            float f1 = fmaxf(fmaf(bf_hi(u.x), sc0.y, sh0.y), 0.f);
            float f2 = fmaxf(fmaf(bf_lo(u.y), sc0.z, sh0.z), 0.f);
            float f3 = fmaxf(fmaf(bf_hi(u.y), sc0.w, sh0.w), 0.f);
            float f4 = fmaxf(fmaf(bf_lo(u.z), sc1.x, sh1.x), 0.f);
            float f5 = fmaxf(fmaf(bf_hi(u.z), sc1.y, sh1.y), 0.f);
            float f6 = fmaxf(fmaf(bf_lo(u.w), sc1.z, sh1.z), 0.f);
            float f7 = fmaxf(fmaf(bf_hi(u.w), sc1.w, sh1.w), 0.f);
            af[0] = (short)f2bf(f0); af[1] = (short)f2bf(f1);
            af[2] = (short)f2bf(f2); af[3] = (short)f2bf(f3);
            af[4] = (short)f2bf(f4); af[5] = (short)f2bf(f5);
            af[6] = (short)f2bf(f6); af[7] = (short)f2bf(f7);
        }
        #pragma unroll
        for (int nt = 0; nt < 8; nt++) {
            bf16x8 bfr = *(const bf16x8*)&WT[(size_t)(nt * 16 + lm) * 128 + kb];
            acc[nt] = __builtin_amdgcn_mfma_f32_16x16x32_bf16(af, bfr, acc[nt], 0, 0, 0);
        }
    }

    const int orow0 = m0 + lq * 4;
    #pragma unroll
    for (int r = 0; r < 4; r++) {
        const int orow = orow0 + r;
        if (orow < n) {
            const float s = dinv[orow];
            #pragma unroll
            for (int nt = 0; nt < 8; nt++)
                C[(size_t)orow * 128 + nt * 16 + lm] = f2bf(acc[nt][r] * s);
        }
    }
}

// ---------------- gather-aggregate: wave per node, uint4 lanes --------------
// lane = (q, eg): q = lane&15 -> 16B chunk (feats 8q..8q+7); eg = lane>>4 ->
// edge slot. 4 edges per wave-load; shfl-reduce across eg at the end.
__global__ __launch_bounds__(256) void k_gather(
        const uint* __restrict__ hs, const int* __restrict__ offs,
        const int* __restrict__ csr, const float* __restrict__ dinv,
        const float* __restrict__ bias, uint* __restrict__ out, int n) {
    const int node = (blockIdx.x * 256 + threadIdx.x) >> 6;
    const int lane = threadIdx.x & 63;
    if (node >= n) return;
    const int q  = lane & 15;
    const int eg = lane >> 4;
    const int beg = offs[node], end = offs[node + 1];
    const uint4* hs4 = (const uint4*)hs;

    float acc[8];
    if (eg == 0) {                               // self loop (prescaled rows)
        uint4 sv = hs4[(size_t)node * 16 + q];
        acc[0] = bf_lo(sv.x); acc[1] = bf_hi(sv.x);
        acc[2] = bf_lo(sv.y); acc[3] = bf_hi(sv.y);
        acc[4] = bf_lo(sv.z); acc[5] = bf_hi(sv.z);
        acc[6] = bf_lo(sv.w); acc[7] = bf_hi(sv.w);
    } else {
        #pragma unroll
        for (int j = 0; j < 8; j++) acc[j] = 0.f;
    }

    for (int e = beg; e < end; e += 4) {
        const int myE = e + eg;
        if (myE < end) {
            const int s = csr[myE];
            uint4 v = hs4[(size_t)s * 16 + q];
            acc[0] += bf_lo(v.x); acc[1] += bf_hi(v.x);
            acc[2] += bf_lo(v.y); acc[3] += bf_hi(v.y);
            acc[4] += bf_lo(v.z); acc[5] += bf_hi(v.z);
            acc[6] += bf_lo(v.w); acc[7] += bf_hi(v.w);
        }
    }

    #pragma unroll
    for (int j = 0; j < 8; j++) {
        acc[j] += __shfl_xor(acc[j], 16);
        acc[j] += __shfl_xor(acc[j], 32);
    }

    if (eg == 0) {
        const float di = dinv[node];
        const float4 b0 = *(const float4*)&bias[q * 8];
        const float4 b1 = *(const float4*)&bias[q * 8 + 4];
        uint4 o;
        o.x = (uint)f2bf(fmaf(di, acc[0], b0.x)) | ((uint)f2bf(fmaf(di, acc[1], b0.y)) << 16);
        o.y = (uint)f2bf(fmaf(di, acc[2], b0.z)) | ((uint)f2bf(fmaf(di, acc[3], b0.w)) << 16);
        o.z = (uint)f2bf(fmaf(di, acc[4], b1.x)) | ((uint)f2bf(fmaf(di, acc[5], b1.y)) << 16);
        o.w = (uint)f2bf(fmaf(di, acc[6], b1.z)) | ((uint)f2bf(fmaf(di, acc[7], b1.w)) << 16);
        ((uint4*)out)[(size_t)node * 16 + q] = o;
    }
}

// ---------------- BN stats (packed uint loads) ----------------
__global__ __launch_bounds__(256) void k_stats(
        const uint* __restrict__ h, int n, float* __restrict__ sums) {
    const int j   = threadIdx.x & 63;
    const int sub = threadIdx.x >> 6;
    float slo = 0.f, s2lo = 0.f, shi = 0.f, s2hi = 0.f;
    for (int r = blockIdx.x * 4 + sub; r < n; r += gridDim.x * 4) {
        uint u = h[(size_t)r * 64 + j];
        float a = bf_lo(u), b = bf_hi(u);
        slo += a; s2lo = fmaf(a, a, s2lo);
        shi += b; s2hi = fmaf(b, b, s2hi);
    }
    __shared__ float sh[4][256];
    sh[0][threadIdx.x] = slo; sh[1][threadIdx.x] = s2lo;
    sh[2][threadIdx.x] = shi; sh[3][threadIdx.x] = s2hi;
    __syncthreads();
    if (sub == 0) {
        float a0 = 0.f, a1 = 0.f, a2 = 0.f, a3 = 0.f;
        #pragma unroll
        for (int t = 0; t < 4; t++) {
            a0 += sh[0][t * 64 + j]; a1 += sh[1][t * 64 + j];
            a2 += sh[2][t * 64 + j]; a3 += sh[3][t * 64 + j];
        }
        atomicAdd(&sums[2 * j],           a0);
        atomicAdd(&sums[128 + 2 * j],     a1);
        atomicAdd(&sums[2 * j + 1],       a2);
        atomicAdd(&sums[128 + 2 * j + 1], a3);
    }
}

// ---------------- head (BN2 derived in-block) --------------
__global__ __launch_bounds__(1024) void k_final(
        const uint* __restrict__ h, const float* __restrict__ sums,
        const float* __restrict__ g, const float* __restrict__ be,
        const float* __restrict__ Wl, const float* __restrict__ bl,
        float* __restrict__ out, int n, float invn) {
    __shared__ float ssl[256];
    const int t = threadIdx.x;
    if (t < 128) {
        float mean = sums[t] * invn;
        float var  = sums[128 + t] * invn - mean * mean;
        float inv  = rsqrtf(var + 1e-5f);
        float sc   = g[t] * inv;
        ssl[t]       = sc;
        ssl[128 + t] = be[t] - mean * sc;
    }
    __syncthreads();
    int node = (blockIdx.x * 1024 + t) >> 6;
    int lane = t & 63;
    if (node >= n) return;
    int c = lane * 2;
    uint v = h[(size_t)node * 64 + lane];
    float a0 = fmaxf(fmaf(bf_lo(v), ssl[c],     ssl[128 + c]),     0.f);
    float a1 = fmaxf(fmaf(bf_hi(v), ssl[c + 1], ssl[128 + c + 1]), 0.f);
    float p = a0 * Wl[c] + a1 * Wl[c + 1];
    #pragma unroll
    for (int o = 32; o; o >>= 1) p += __shfl_xor(p, o);
    if (lane == 0) {
        float z = fmaxf(p + bl[0], 0.f);
        out[node] = 1.f / (1.f + expf(-z));
    }
}

extern "C" void kernel_launch(void* const* d_in, const int* in_sizes, int n_in,
                              void* d_out, int out_size, void* d_ws, size_t ws_size,
                              hipStream_t stream) {
    const float* x   = (const float*)d_in[0];
    const int*   ei  = (const int*)d_in[1];
    const float* W1  = (const float*)d_in[2];
    const float* b1  = (const float*)d_in[3];
    const float* g1  = (const float*)d_in[4];
    const float* be1 = (const float*)d_in[5];
    const float* W2  = (const float*)d_in[6];
    const float* b2  = (const float*)d_in[7];
    const float* g2  = (const float*)d_in[8];
    const float* be2 = (const float*)d_in[9];
    const float* Wl  = (const float*)d_in[10];
    const float* bl  = (const float*)d_in[11];

    const int N = in_sizes[0] / 128;
    const int E = in_sizes[1] / 2;
    const int* src  = ei;
    const int* dstp = ei + E;

    const int NBKT  = (N + 255) >> 8;
    const int n2    = NBKT * 256;
    const int NB2   = (n2 + 1023) / 1024;
    const int CHUNK = (E + 255) / 256;

    char* ws = (char*)d_ws;
    size_t off = 0;
    auto alloc = [&](size_t bytes) {
        void* p = ws + off;
        off += (bytes + 255) & ~(size_t)255;
        return p;
    };
    float*  dinv   = (float*) alloc((size_t)N * 4);
    int*    offs   = (int*)   alloc((size_t)(N + 1) * 4);
    int*    cnt2d  = (int*)   alloc((size_t)n2 * 4);
    int*    cnt2dx = (int*)   alloc((size_t)n2 * 4);
    int*    bsum   = (int*)   alloc(1024 * 4);
    uint*   ebuf   = (uint*)  alloc((size_t)E * 4);
    int*    csr    = (int*)   alloc((size_t)E * 4);
    float*  sums   = (float*) alloc(512 * 4);
    ushort* WT1    = (ushort*)alloc(128 * 128 * 2);
    ushort* WT2    = (ushort*)alloc(128 * 128 * 2);
    ushort* hbuf   = (ushort*)alloc((size_t)N * 128 * 2);
    ushort* abuf   = (ushort*)alloc((size_t)N * 128 * 2);

    const float invn = 1.f / (float)N;

    // ---- CSR build (bucketed counting sort) + fused weight prep ----
    k_bcount    <<<384, 256, 0, stream>>>(dstp, E, CHUNK, cnt2d, NBKT,
                                          W1, W2, WT1, WT2, sums);
    k_scan_local<<<NB2, 256, 0, stream>>>(cnt2d, n2, cnt2dx, bsum);
    k_scan_add  <<<NB2, 256, 0, stream>>>(cnt2dx, n2, bsum, NB2);
    k_bscatter  <<<256, 256, 0, stream>>>(src, dstp, E, CHUNK, cnt2d, cnt2dx, ebuf, NBKT);
    k_bcsr      <<<NBKT, 256, 0, stream>>>(ebuf, cnt2dx, E, N, NBKT, dinv, offs, csr);

    // ---- layer 1 ----
    k_gemm<0> <<<(N + 63) / 64, 256, 0, stream>>>(x, WT1, nullptr, nullptr, nullptr, dinv, hbuf, N, invn);
    k_gather  <<<(N + 3) / 4, 256, 0, stream>>>((const uint*)hbuf, offs, csr, dinv, b1, (uint*)abuf, N);
    k_stats   <<<512, 256, 0, stream>>>((const uint*)abuf, N, sums);

    // ---- layer 2 (BN1+ReLU and BN-param derivation fused into GEMM2) ----
    k_gemm<1> <<<(N + 63) / 64, 256, 0, stream>>>(abuf, WT2, sums, g1, be1, dinv, hbuf, N, invn);
    k_gather  <<<(N + 3) / 4, 256, 0, stream>>>((const uint*)hbuf, offs, csr, dinv, b2, (uint*)abuf, N);
    k_stats   <<<512, 256, 0, stream>>>((const uint*)abuf, N, sums + 256);

    // ---- head (BN2 derived in-block) ----
    k_final<<<(N + 15) / 16, 1024, 0, stream>>>((const uint*)abuf, sums + 256, g2, be2, Wl, bl, (float*)d_out, N, invn);
}